// Round 7
// baseline (215.616 us; speedup 1.0000x reference)
//
#include <hip/hip_runtime.h>
#include <hip/hip_bf16.h>

#define L2E 1.4426950408889634f
#define LN2 0.6931471805599453f

__device__ __forceinline__ float fexp2(float x) { return __builtin_amdgcn_exp2f(x); }
__device__ __forceinline__ float flog2(float x) { return __builtin_amdgcn_logf(x); }
__device__ __forceinline__ int uniform(int x) { return __builtin_amdgcn_readfirstlane(x); }
__device__ __forceinline__ float sigmoidf_(float v) { return 1.f / (1.f + fexp2(-v * L2E)); }
__device__ __forceinline__ float softplusf_(float t) {
    return (t > 20.f) ? t : LN2 * flog2(1.f + fexp2(t * L2E));
}

// ---------------- workspace layout (floats), total 26,411,008 = 105.6 MB (pool = 256 MiB) ----
constexpr size_t O_M   = 0;          // [32][1024] LN mean
constexpr size_t O_RS  = 32768;      // [32][1024] LN rstd
constexpr size_t O_G   = 65536;      // [32][128][1024] xi
constexpr size_t O_Z   = 4259840;    // [32][128][1024] z
constexpr size_t O_XC  = 8454144;    // [32][128][1024] conv+silu out
constexpr size_t O_BM  = 12648448;   // [32][16][1024]
constexpr size_t O_CM  = 13172736;   // [32][16][1024]
constexpr size_t O_HP  = 13828096;   // [32][32][2][2048]: per-chunk P (→h_init) and E
constexpr size_t O_DT  = 18022400;   // [32][128][1024] dt (post-softplus)
constexpr size_t O_DX  = 22216704;   // [32][128][1024] dx = dt*xc

// ================= K1: LN + in-proj GEMM W[256,64] @ XN[64,1024], jb-merged =================
// grid 512 = 32 seq * 16 pb; block 256 (16 jt x 16 pt). X staged + LN computed ONCE,
// W tile re-staged per jb (4x).
__global__ __launch_bounds__(256) void k1_ln_inproj(
    const float* __restrict__ x0, const float* __restrict__ x1,
    const float* __restrict__ x2, const float* __restrict__ x3,
    const float* __restrict__ win,
    const float* __restrict__ g1, const float* __restrict__ be1,
    const float* __restrict__ g2, const float* __restrict__ be2,
    const float* __restrict__ g3, const float* __restrict__ be3,
    const float* __restrict__ g4, const float* __restrict__ be4,
    float* __restrict__ ws)
{
    __shared__ float sX[64 * 68];
    __shared__ float sW[64 * 68];
    __shared__ float sM[64], sR[64];
    int bid = blockIdx.x;
    int seq = bid >> 4, pb = bid & 15;
    int branch = seq >> 3, b = seq & 7;
    int tid = threadIdx.x;
    int lane = tid & 63;
    int wq = uniform(tid >> 6);
    const float* xin = (branch==0)?x0:(branch==1)?x1:(branch==2)?x2:x3;
    const float* gam = (branch==0)?g1:(branch==1)?g2:(branch==2)?g3:g4;
    const float* bet = (branch==0)?be1:(branch==1)?be2:(branch==2)?be3:be4;
    const float* xb = xin + (size_t)b * 65536;

#pragma unroll
    for (int r = 0; r < 16; ++r) {
        int row = r * 4 + wq;                         // uniform per wave
        sX[row * 68 + lane] = xb[(size_t)row * 1024 + pb * 64 + lane];
    }
    __syncthreads();
    if (tid < 64) {
        float sum = 0.f, sq = 0.f;
#pragma unroll
        for (int c = 0; c < 64; ++c) {
            float v = sX[c * 68 + tid];
            sum += v; sq += v * v;
        }
        float mean = sum * (1.f/64.f);
        float var  = sq * (1.f/64.f) - mean * mean;
        float rs   = rsqrtf(var + 1e-5f);
        sM[tid] = mean; sR[tid] = rs;
        ws[O_M  + (size_t)seq * 1024 + pb * 64 + tid] = mean;
        ws[O_RS + (size_t)seq * 1024 + pb * 64 + tid] = rs;
    }
    __syncthreads();
#pragma unroll
    for (int r = 0; r < 16; ++r) {
        int c = r * 4 + wq;
        float v = sX[c * 68 + lane];
        sX[c * 68 + lane] = (v - sM[lane]) * sR[lane] * gam[c] + bet[c];
    }
    __syncthreads();

    int jt = tid >> 4, pt = tid & 15;
    int p0 = pb * 64 + pt * 4;
    float* xi = ws + O_G + (size_t)seq * 131072;
    float* zz = ws + O_Z + (size_t)seq * 131072;

    for (int jb = 0; jb < 4; ++jb) {
#pragma unroll
        for (int r = 0; r < 16; ++r) {
            int row = r * 4 + wq;
            sW[lane * 68 + row] = win[(size_t)(jb * 64 + row) * 64 + lane];
        }
        __syncthreads();
        float acc[4][4];
#pragma unroll
        for (int i = 0; i < 4; ++i)
#pragma unroll
            for (int j = 0; j < 4; ++j) acc[i][j] = 0.f;
        for (int c = 0; c < 64; ++c) {
            float4 wv = *(const float4*)&sW[c * 68 + jt * 4];
            float4 xv = *(const float4*)&sX[c * 68 + pt * 4];
            float w[4] = {wv.x, wv.y, wv.z, wv.w};
            float x[4] = {xv.x, xv.y, xv.z, xv.w};
#pragma unroll
            for (int i = 0; i < 4; ++i)
#pragma unroll
                for (int j = 0; j < 4; ++j) acc[i][j] += w[i] * x[j];
        }
#pragma unroll
        for (int ji = 0; ji < 4; ++ji) {
            int j = jb * 64 + jt * 4 + ji;
            float4 v = make_float4(acc[ji][0], acc[ji][1], acc[ji][2], acc[ji][3]);
            if (j < 128) *(float4*)&xi[(size_t)j * 1024 + p0] = v;
            else         *(float4*)&zz[(size_t)(j - 128) * 1024 + p0] = v;
        }
        __syncthreads();
    }
}

// ================= K2: conv4 + SiLU + x-proj(128->36) + dt/dx precompute =================
// grid 512 = 32 seq * 16 ptile; block 256 = 4 waves x 64 p-lanes.
// Round-7 revert: phase-5 (chunk-local scan) moved BACK to standalone k3a — fusing it here
// ran the exp2-heavy scan at 2 blocks/CU (75.8 KB LDS) and regressed k2 to 59 us.
__global__ __launch_bounds__(256) void k2_conv_proj(
    const float* __restrict__ wconv, const float* __restrict__ bconv,
    const float* __restrict__ wxp,
    const float* __restrict__ wdt, const float* __restrict__ bdt,
    float* __restrict__ ws)
{
    __shared__ float sX[128 * 68];       // [d][c], c <-> p = p0-3+c
    __shared__ float sWr[4 * 128 * 12];  // per-wave replica: [wq][d][jj], jj=0..8
    __shared__ __align__(16) float sDtp4[64 * 4];
    int bid = blockIdx.x;
    int seq = bid >> 4, ptile = bid & 15;
    int tid = threadIdx.x;
    int lane = tid & 63;
    int wq = uniform(tid >> 6);
    int p0 = ptile * 64;
    int p  = p0 + lane;
    int j0 = wq * 9;

    const float* xirow = ws + O_G  + (size_t)seq * 131072;
    float*       xcrow = ws + O_XC + (size_t)seq * 131072;

    // ---- phase 1: stage xi tile + weight replicas ----
#pragma unroll 4
    for (int r = 0; r < 32; ++r) {
        int d = r * 4 + wq;                            // uniform per wave
        const float* row = xirow + (size_t)d * 1024;
        int gp = p0 - 3 + lane;
        sX[d * 68 + lane] = (gp >= 0) ? row[gp] : 0.f;
        if (lane < 3) sX[d * 68 + 64 + lane] = row[p0 + 61 + lane];
    }
#pragma unroll
    for (int jj = 0; jj < 9; ++jj) {
#pragma unroll
        for (int half = 0; half < 2; ++half) {
            int d = half * 64 + lane;
            sWr[(wq * 128 + d) * 12 + jj] = wxp[(size_t)(j0 + jj) * 128 + d];
        }
    }
    __syncthreads();

    // ---- phase 2: conv4 + silu ----
#pragma unroll 2
    for (int dd = 0; dd < 32; ++dd) {
        int d = wq * 32 + dd;                          // uniform
        float4 wc = *(const float4*)&wconv[d * 4];
        float v = bconv[d];
        float* rowl = &sX[d * 68];
        v += rowl[lane + 0] * wc.x;
        v += rowl[lane + 1] * wc.y;
        v += rowl[lane + 2] * wc.z;
        v += rowl[lane + 3] * wc.w;
        v = v * sigmoidf_(v);
        xcrow[(size_t)d * 1024 + p] = v;
        rowl[lane + 3] = v;                            // in-place xc
    }
    __syncthreads();

    // ---- phase 3: x-proj, K = 128; weights via LDS broadcast ----
    float acc[9];
#pragma unroll
    for (int jj = 0; jj < 9; ++jj) acc[jj] = 0.f;
#pragma unroll 4
    for (int d = 0; d < 128; ++d) {
        float xcv = sX[d * 68 + 3 + lane];
        const float* wr = &sWr[(wq * 128 + d) * 12];
        float4 wA = *(const float4*)wr;
        float4 wB = *(const float4*)(wr + 4);
        float  w8 = wr[8];
        acc[0] += wA.x * xcv; acc[1] += wA.y * xcv;
        acc[2] += wA.z * xcv; acc[3] += wA.w * xcv;
        acc[4] += wB.x * xcv; acc[5] += wB.y * xcv;
        acc[6] += wB.z * xcv; acc[7] += wB.w * xcv;
        acc[8] += w8 * xcv;
    }

    float* Bm = ws + O_BM + (size_t)seq * 16384;
    float* Cm = ws + O_CM + (size_t)seq * 16384;
#pragma unroll
    for (int jj = 0; jj < 9; ++jj) {
        int j = j0 + jj;
        if (j < 4) continue;                           // dtp consumed in phase 4
        float t = acc[jj];
        if (j < 20) Bm[(size_t)(j - 4)  * 1024 + p] = t;
        else        Cm[(size_t)(j - 20) * 1024 + p] = t;
    }

    // ---- phase 4: dt + dx ----
    if (wq == 0)
        *(float4*)&sDtp4[lane * 4] = make_float4(acc[0], acc[1], acc[2], acc[3]);
    __syncthreads();
    float* dtg = ws + O_DT + (size_t)seq * 131072;
    float* dxg = ws + O_DX + (size_t)seq * 131072;
    float4 qv = *(const float4*)&sDtp4[lane * 4];
#pragma unroll 4
    for (int dd = 0; dd < 32; ++dd) {
        int d = wq * 32 + dd;                          // uniform
        float4 wv = *(const float4*)&wdt[d * 4];       // uniform scalar loads
        float t = bdt[d] + qv.x*wv.x + qv.y*wv.y + qv.z*wv.z + qv.w*wv.w;
        float dt = softplusf_(t);
        float dx = dt * sX[d * 68 + 3 + lane];
        dtg[(size_t)d * 1024 + p] = dt;
        dxg[(size_t)d * 1024 + p] = dx;
    }
}

// ---------------- a2 preload (A coefficients in exp2 domain) ----------------
__device__ __forceinline__ void a2_preload(const float* alog, int d0, int s0, float* a2)
{
    float4 a0 = *(const float4*)(alog + d0 * 16 + s0);
    float4 a1 = *(const float4*)(alog + (d0 + 1) * 16 + s0);
    a2[0] = -fexp2(a0.x * L2E) * L2E; a2[1] = -fexp2(a0.y * L2E) * L2E;
    a2[2] = -fexp2(a0.z * L2E) * L2E; a2[3] = -fexp2(a0.w * L2E) * L2E;
    a2[4] = -fexp2(a1.x * L2E) * L2E; a2[5] = -fexp2(a1.y * L2E) * L2E;
    a2[6] = -fexp2(a1.z * L2E) * L2E; a2[7] = -fexp2(a1.w * L2E) * L2E;
}

// ================= K3A: local scan (h0=0); emit per-chunk P and E =================
// grid 1024 = 32 seq * 32 ch; block 256; tiny LDS -> high occupancy (the scan's exp2 chain
// needs TLP, not fusion). dt/dx from K2 via L2/L3-hot global float4 reads.
__global__ __launch_bounds__(256) void k3a_scan(const float* __restrict__ alog,
                                                float* __restrict__ ws)
{
    __shared__ __align__(16) float sB[32 * 16];
    int bid = blockIdx.x;
    int seq = bid >> 5, ch = bid & 31;
    int lb = ch * 32;
    int tid = threadIdx.x;
    int d0 = (tid >> 2) * 2, s0 = (tid & 3) * 4;

    float a2[8];
    a2_preload(alog, d0, s0, a2);

    const float* Bmg = ws + O_BM + (size_t)seq * 16384;
    for (int i = tid; i < 512; i += 256) {
        int s = i >> 5, li = i & 31;
        sB[li * 16 + s] = Bmg[(size_t)s * 1024 + lb + li];
    }
    __syncthreads();

    const float* r0t = ws + O_DT + (size_t)seq * 131072 + (size_t)d0 * 1024 + lb;
    const float* r1t = r0t + 1024;
    const float* r0x = ws + O_DX + (size_t)seq * 131072 + (size_t)d0 * 1024 + lb;
    const float* r1x = r0x + 1024;

    float h[8];
#pragma unroll
    for (int i = 0; i < 8; ++i) h[i] = 0.f;
    float sdt0 = 0.f, sdt1 = 0.f;
    for (int q4 = 0; q4 < 8; ++q4) {
        float4 t0 = *(const float4*)&r0t[q4 * 4];
        float4 t1 = *(const float4*)&r1t[q4 * 4];
        float4 x0 = *(const float4*)&r0x[q4 * 4];
        float4 x1 = *(const float4*)&r1x[q4 * 4];
        float t0a[4] = {t0.x, t0.y, t0.z, t0.w};
        float t1a[4] = {t1.x, t1.y, t1.z, t1.w};
        float x0a[4] = {x0.x, x0.y, x0.z, x0.w};
        float x1a[4] = {x1.x, x1.y, x1.z, x1.w};
#pragma unroll
        for (int k = 0; k < 4; ++k) {
            int li = q4 * 4 + k;
            float dt0 = t0a[k], dt1 = t1a[k];
            float dx0 = x0a[k], dx1 = x1a[k];
            float4 Bv = *(const float4*)&sB[li * 16 + s0];
            float bv[4] = {Bv.x, Bv.y, Bv.z, Bv.w};
            sdt0 += dt0; sdt1 += dt1;
#pragma unroll
            for (int ss = 0; ss < 4; ++ss) {
                float e0 = fexp2(dt0 * a2[ss]);
                h[ss] = e0 * h[ss] + dx0 * bv[ss];
                float e1 = fexp2(dt1 * a2[4 + ss]);
                h[4 + ss] = e1 * h[4 + ss] + dx1 * bv[ss];
            }
        }
    }
    float* hp = ws + O_HP + (size_t)(seq * 32 + ch) * 4096;
#pragma unroll
    for (int ss = 0; ss < 4; ++ss) {
        hp[d0 * 16 + s0 + ss]              = fexp2(a2[ss] * sdt0);
        hp[(d0 + 1) * 16 + s0 + ss]        = fexp2(a2[4 + ss] * sdt1);
        hp[2048 + d0 * 16 + s0 + ss]       = h[ss];
        hp[2048 + (d0 + 1) * 16 + s0 + ss] = h[4 + ss];
    }
}

// phase B: sequential prefix compose. grid 256 = 32 seq * 8 dgroups, 1 state/thread.
__global__ __launch_bounds__(256) void k3b_compose(float* __restrict__ ws)
{
    int seq = blockIdx.x >> 3, dg = blockIdx.x & 7;
    int idx = dg * 256 + threadIdx.x;
    float h = 0.f;
    float* hpb = ws + O_HP + (size_t)seq * 32 * 4096;
    float P = hpb[idx];
    float E = hpb[2048 + idx];
    for (int c = 0; c < 32; ++c) {
        float* hp = hpb + (size_t)c * 4096;
        float Pn = 0.f, En = 0.f;
        if (c < 31) { Pn = hp[4096 + idx]; En = hp[4096 + 2048 + idx]; }
        hp[idx] = h;
        h = P * h + E;
        P = Pn; E = En;
    }
}

// ================= K3CD: rescan + gate + out-proj + skip =================
// grid 1024 = 32 seq * 32 ch; block 256. LDS 22.5 KB.
__global__ __launch_bounds__(256) void k3cd(
    const float* __restrict__ alog,
    const float* __restrict__ x0, const float* __restrict__ x1,
    const float* __restrict__ x2, const float* __restrict__ x3,
    const float* __restrict__ g1, const float* __restrict__ be1,
    const float* __restrict__ g2, const float* __restrict__ be2,
    const float* __restrict__ g3, const float* __restrict__ be3,
    const float* __restrict__ g4, const float* __restrict__ be4,
    const float* __restrict__ dpar, const float* __restrict__ woutp,
    const float* __restrict__ skipp, float* __restrict__ ws,
    float* __restrict__ out)
{
    __shared__ __align__(16) float sY[128 * 36];     // y, then gated g
    __shared__ __align__(16) float sB[32 * 16];
    __shared__ __align__(16) float sC[32 * 16];
    int bid = blockIdx.x;
    int seq = bid >> 5, ch = bid & 31;
    int branch = seq >> 3, b = seq & 7;
    int lb = ch * 32;
    int tid = threadIdx.x;
    int sq = tid & 3;
    int d0 = (tid >> 2) * 2, s0 = sq * 4;

    float a2[8];
    a2_preload(alog, d0, s0, a2);

    const float* Bmg = ws + O_BM + (size_t)seq * 16384;
    const float* Cmg = ws + O_CM + (size_t)seq * 16384;
    for (int i = tid; i < 512; i += 256) {
        int s = i >> 5, li = i & 31;
        sB[li * 16 + s] = Bmg[(size_t)s * 1024 + lb + li];
        sC[li * 16 + s] = Cmg[(size_t)s * 1024 + lb + li];
    }

    const float* hp = ws + O_HP + (size_t)(seq * 32 + ch) * 4096;
    float4 H0 = *(const float4*)&hp[d0 * 16 + s0];
    float4 H1 = *(const float4*)&hp[(d0 + 1) * 16 + s0];
    float h[8] = {H0.x, H0.y, H0.z, H0.w, H1.x, H1.y, H1.z, H1.w};
    __syncthreads();

    const float* r0t = ws + O_DT + (size_t)seq * 131072 + (size_t)d0 * 1024 + lb;
    const float* r1t = r0t + 1024;
    const float* r0x = ws + O_DX + (size_t)seq * 131072 + (size_t)d0 * 1024 + lb;
    const float* r1x = r0x + 1024;

    // ---- rescan: y into sY (stride 36) ----
    for (int q4 = 0; q4 < 8; ++q4) {
        float4 t0 = *(const float4*)&r0t[q4 * 4];
        float4 t1 = *(const float4*)&r1t[q4 * 4];
        float4 x0v = *(const float4*)&r0x[q4 * 4];
        float4 x1v = *(const float4*)&r1x[q4 * 4];
        float t0a[4] = {t0.x, t0.y, t0.z, t0.w};
        float t1a[4] = {t1.x, t1.y, t1.z, t1.w};
        float x0a[4] = {x0v.x, x0v.y, x0v.z, x0v.w};
        float x1a[4] = {x1v.x, x1v.y, x1v.z, x1v.w};
#pragma unroll
        for (int k = 0; k < 4; ++k) {
            int li = q4 * 4 + k;
            float dt0 = t0a[k], dt1 = t1a[k];
            float dx0 = x0a[k], dx1 = x1a[k];
            float4 Bv = *(const float4*)&sB[li * 16 + s0];
            float4 Cv = *(const float4*)&sC[li * 16 + s0];
            float bv[4] = {Bv.x, Bv.y, Bv.z, Bv.w};
            float cv[4] = {Cv.x, Cv.y, Cv.z, Cv.w};
            float acc0 = 0.f, acc1 = 0.f;
#pragma unroll
            for (int ss = 0; ss < 4; ++ss) {
                float e0 = fexp2(dt0 * a2[ss]);
                h[ss] = e0 * h[ss] + dx0 * bv[ss];
                acc0 += h[ss] * cv[ss];
                float e1 = fexp2(dt1 * a2[4 + ss]);
                h[4 + ss] = e1 * h[4 + ss] + dx1 * bv[ss];
                acc1 += h[4 + ss] * cv[ss];
            }
            acc0 += __shfl_xor(acc0, 1); acc0 += __shfl_xor(acc0, 2);
            acc1 += __shfl_xor(acc1, 1); acc1 += __shfl_xor(acc1, 2);
            if (sq == 0) {
                sY[d0 * 36 + li]       = acc0;
                sY[(d0 + 1) * 36 + li] = acc1;
            }
        }
    }
    __syncthreads();

    // ---- gate in place: g = (y + D*xc) * silu(z) ----
    const float* zzg = ws + O_Z  + (size_t)seq * 131072;
    const float* xcg = ws + O_XC + (size_t)seq * 131072;
    for (int i = tid; i < 4096; i += 256) {
        int d = i >> 5, li = i & 31;
        float zv  = zzg[(size_t)d * 1024 + lb + li];
        float xcv = xcg[(size_t)d * 1024 + lb + li];
        float yv  = sY[d * 36 + li];
        sY[d * 36 + li] = (yv + dpar[d] * xcv) * (zv * sigmoidf_(zv));
    }
    __syncthreads();

    // ---- out-proj GEMM: out[64c][32p] = Wout[64][128] @ g[128][32] ----
    int ctt = tid >> 3;          // c0 = 2*ctt
    int ptq = tid & 7;           // p0 = 4*ptq
    int c0 = ctt * 2;
    const float* w0p = woutp + (size_t)c0 * 128;
    const float* w1p = w0p + 128;
    float acc[2][4];
#pragma unroll
    for (int i = 0; i < 2; ++i)
#pragma unroll
        for (int j = 0; j < 4; ++j) acc[i][j] = 0.f;
    for (int d4 = 0; d4 < 32; ++d4) {
        float4 wa = *(const float4*)&w0p[d4 * 4];
        float4 wb = *(const float4*)&w1p[d4 * 4];
        float waa[4] = {wa.x, wa.y, wa.z, wa.w};
        float wba[4] = {wb.x, wb.y, wb.z, wb.w};
#pragma unroll
        for (int k = 0; k < 4; ++k) {
            int d = d4 * 4 + k;
            float4 gv = *(const float4*)&sY[d * 36 + ptq * 4];
            acc[0][0] += waa[k] * gv.x; acc[0][1] += waa[k] * gv.y;
            acc[0][2] += waa[k] * gv.z; acc[0][3] += waa[k] * gv.w;
            acc[1][0] += wba[k] * gv.x; acc[1][1] += wba[k] * gv.y;
            acc[1][2] += wba[k] * gv.z; acc[1][3] += wba[k] * gv.w;
        }
    }

    // ---- epilogue: + skip * xn ----
    const float* xin = (branch==0)?x0:(branch==1)?x1:(branch==2)?x2:x3;
    const float* gam = (branch==0)?g1:(branch==1)?g2:(branch==2)?g3:g4;
    const float* bet = (branch==0)?be1:(branch==1)?be2:(branch==2)?be3:be4;
    const float* xb = xin + (size_t)b * 65536;
    int pp = lb + ptq * 4;
    float skipv = skipp[0];
    float4 m4 = *(const float4*)&ws[O_M  + (size_t)seq * 1024 + pp];
    float4 r4 = *(const float4*)&ws[O_RS + (size_t)seq * 1024 + pp];
    float mm[4] = {m4.x, m4.y, m4.z, m4.w};
    float rr[4] = {r4.x, r4.y, r4.z, r4.w};
#pragma unroll
    for (int ci = 0; ci < 2; ++ci) {
        int c = c0 + ci;
        float4 xv = *(const float4*)&xb[(size_t)c * 1024 + pp];
        float xvv[4] = {xv.x, xv.y, xv.z, xv.w};
        float gc = gam[c], bc = bet[c];
        float o[4];
#pragma unroll
        for (int pi = 0; pi < 4; ++pi) {
            float xn = (xvv[pi] - mm[pi]) * rr[pi] * gc + bc;
            o[pi] = acc[ci][pi] + skipv * xn;
        }
        *(float4*)&out[((size_t)b * 256 + branch * 64 + c) * 1024 + pp] =
            make_float4(o[0], o[1], o[2], o[3]);
    }
}

// ---------------- launch ----------------
extern "C" void kernel_launch(void* const* d_in, const int* in_sizes, int n_in,
                              void* d_out, int out_size, void* d_ws, size_t ws_size,
                              hipStream_t stream) {
    float* ws = (float*)d_ws;
    auto f = [&](int i) { return (const float*)d_in[i]; };
    hipLaunchKernelGGL(k1_ln_inproj, dim3(512), dim3(256), 0, stream,
        f(0), f(1), f(2), f(3), f(13),
        f(4), f(5), f(6), f(7), f(8), f(9), f(10), f(11), ws);
    hipLaunchKernelGGL(k2_conv_proj, dim3(512), dim3(256), 0, stream,
        f(14), f(15), f(16), f(17), f(18), ws);
    hipLaunchKernelGGL(k3a_scan, dim3(1024), dim3(256), 0, stream, f(19), ws);
    hipLaunchKernelGGL(k3b_compose, dim3(256), dim3(256), 0, stream, ws);
    hipLaunchKernelGGL(k3cd, dim3(1024), dim3(256), 0, stream,
        f(19),
        f(0), f(1), f(2), f(3),
        f(4), f(5), f(6), f(7), f(8), f(9), f(10), f(11),
        f(20), f(21), f(12), ws, (float*)d_out);
}

// Round 10
// 204.851 us; speedup vs baseline: 1.0525x; 1.0525x over previous
//
#include <hip/hip_runtime.h>
#include <hip/hip_bf16.h>

#define L2E 1.4426950408889634f
#define LN2 0.6931471805599453f

__device__ __forceinline__ float fexp2(float x) { return __builtin_amdgcn_exp2f(x); }
__device__ __forceinline__ float flog2(float x) { return __builtin_amdgcn_logf(x); }
__device__ __forceinline__ int uniform(int x) { return __builtin_amdgcn_readfirstlane(x); }
__device__ __forceinline__ float sigmoidf_(float v) { return 1.f / (1.f + fexp2(-v * L2E)); }
__device__ __forceinline__ float softplusf_(float t) {
    return (t > 20.f) ? t : LN2 * flog2(1.f + fexp2(t * L2E));
}

// ---------------- workspace layout (floats), total 26,411,008 = 105.6 MB (pool = 256 MiB) ----
constexpr size_t O_M   = 0;          // [32][1024] LN mean
constexpr size_t O_RS  = 32768;      // [32][1024] LN rstd
constexpr size_t O_G   = 65536;      // [32][128][1024] xi
constexpr size_t O_Z   = 4259840;    // [32][128][1024] z
constexpr size_t O_XC  = 8454144;    // [32][128][1024] conv+silu out
constexpr size_t O_BM  = 12648448;   // [32][16][1024]
constexpr size_t O_CM  = 13172736;   // [32][16][1024]
constexpr size_t O_HP  = 13828096;   // [32][32][2][2048]: per-chunk P (→h_init) and E
constexpr size_t O_DT  = 18022400;   // [32][128][1024] dt (post-softplus)
constexpr size_t O_DX  = 22216704;   // [32][128][1024] dx = dt*xc

// ================= K1: LN + in-proj GEMM W[256,64] @ XN[64,1024], jb-merged =================
// grid 512 = 32 seq * 16 pb; block 256 (16 jt x 16 pt).
__global__ __launch_bounds__(256) void k1_ln_inproj(
    const float* __restrict__ x0, const float* __restrict__ x1,
    const float* __restrict__ x2, const float* __restrict__ x3,
    const float* __restrict__ win,
    const float* __restrict__ g1, const float* __restrict__ be1,
    const float* __restrict__ g2, const float* __restrict__ be2,
    const float* __restrict__ g3, const float* __restrict__ be3,
    const float* __restrict__ g4, const float* __restrict__ be4,
    float* __restrict__ ws)
{
    __shared__ float sX[64 * 68];
    __shared__ float sW[64 * 68];
    __shared__ float sM[64], sR[64];
    int bid = blockIdx.x;
    int seq = bid >> 4, pb = bid & 15;
    int branch = seq >> 3, b = seq & 7;
    int tid = threadIdx.x;
    int lane = tid & 63;
    int wq = uniform(tid >> 6);
    const float* xin = (branch==0)?x0:(branch==1)?x1:(branch==2)?x2:x3;
    const float* gam = (branch==0)?g1:(branch==1)?g2:(branch==2)?g3:g4;
    const float* bet = (branch==0)?be1:(branch==1)?be2:(branch==2)?be3:be4;
    const float* xb = xin + (size_t)b * 65536;

#pragma unroll
    for (int r = 0; r < 16; ++r) {
        int row = r * 4 + wq;                         // uniform per wave
        sX[row * 68 + lane] = xb[(size_t)row * 1024 + pb * 64 + lane];
    }
    __syncthreads();
    if (tid < 64) {
        float sum = 0.f, sq = 0.f;
#pragma unroll
        for (int c = 0; c < 64; ++c) {
            float v = sX[c * 68 + tid];
            sum += v; sq += v * v;
        }
        float mean = sum * (1.f/64.f);
        float var  = sq * (1.f/64.f) - mean * mean;
        float rs   = rsqrtf(var + 1e-5f);
        sM[tid] = mean; sR[tid] = rs;
        ws[O_M  + (size_t)seq * 1024 + pb * 64 + tid] = mean;
        ws[O_RS + (size_t)seq * 1024 + pb * 64 + tid] = rs;
    }
    __syncthreads();
#pragma unroll
    for (int r = 0; r < 16; ++r) {
        int c = r * 4 + wq;
        float v = sX[c * 68 + lane];
        sX[c * 68 + lane] = (v - sM[lane]) * sR[lane] * gam[c] + bet[c];
    }
    __syncthreads();

    int jt = tid >> 4, pt = tid & 15;
    int p0 = pb * 64 + pt * 4;
    float* xi = ws + O_G + (size_t)seq * 131072;
    float* zz = ws + O_Z + (size_t)seq * 131072;

    for (int jb = 0; jb < 4; ++jb) {
#pragma unroll
        for (int r = 0; r < 16; ++r) {
            int row = r * 4 + wq;
            sW[lane * 68 + row] = win[(size_t)(jb * 64 + row) * 64 + lane];
        }
        __syncthreads();
        float acc[4][4];
#pragma unroll
        for (int i = 0; i < 4; ++i)
#pragma unroll
            for (int j = 0; j < 4; ++j) acc[i][j] = 0.f;
        for (int c = 0; c < 64; ++c) {
            float4 wv = *(const float4*)&sW[c * 68 + jt * 4];
            float4 xv = *(const float4*)&sX[c * 68 + pt * 4];
            float w[4] = {wv.x, wv.y, wv.z, wv.w};
            float x[4] = {xv.x, xv.y, xv.z, xv.w};
#pragma unroll
            for (int i = 0; i < 4; ++i)
#pragma unroll
                for (int j = 0; j < 4; ++j) acc[i][j] += w[i] * x[j];
        }
#pragma unroll
        for (int ji = 0; ji < 4; ++ji) {
            int j = jb * 64 + jt * 4 + ji;
            float4 v = make_float4(acc[ji][0], acc[ji][1], acc[ji][2], acc[ji][3]);
            if (j < 128) *(float4*)&xi[(size_t)j * 1024 + p0] = v;
            else         *(float4*)&zz[(size_t)(j - 128) * 1024 + p0] = v;
        }
        __syncthreads();
    }
}

// ================= K2: conv+silu + x-proj + dt/dx + chunk-local scan (fused, slim LDS) =====
// grid 512 = 32 seq * 16 ptile; block 256 = 4 waves x 64 p-lanes; block covers 2 chunks.
// R8: fusion restored (R6 proved it wins); LDS cut 75.8 -> 53 KB for 3 blocks/CU:
//  - conv via __shfl_up from global (no xi halo tile); xc -> sX[128][64]
//  - sWr stride 12 -> 10 (b64 reads)
//  - sB5 overlays dead sWr after phase 3; phase 5 reads dt/dx from global (same-block L2-hot)
__global__ __launch_bounds__(256) void k2_conv_proj(
    const float* __restrict__ wconv, const float* __restrict__ bconv,
    const float* __restrict__ wxp,
    const float* __restrict__ wdt, const float* __restrict__ bdt,
    const float* __restrict__ alog,
    float* __restrict__ ws)
{
    __shared__ __align__(16) float sX[128 * 64];      // xc [d][p_local]
    __shared__ __align__(16) float sWr[4 * 128 * 10]; // weight replicas; -> sB5 after ph3
    __shared__ __align__(16) float sDtp4[64 * 4];
    float* sB5 = sWr;                                 // [64][20] B rows, overlay

    int bid = blockIdx.x;
    int seq = bid >> 4, ptile = bid & 15;
    int tid = threadIdx.x;
    int lane = tid & 63;
    int wq = uniform(tid >> 6);
    int p0 = ptile * 64;
    int p  = p0 + lane;
    int j0 = wq * 9;

    const float* xirow = ws + O_G  + (size_t)seq * 131072;
    float*       xcrow = ws + O_XC + (size_t)seq * 131072;

    // ---- phase 1: stage weight replicas (stride 10, b64-aligned rows) ----
#pragma unroll
    for (int jj = 0; jj < 9; ++jj) {
#pragma unroll
        for (int half = 0; half < 2; ++half) {
            int d = half * 64 + lane;
            sWr[(wq * 128 + d) * 10 + jj] = wxp[(size_t)(j0 + jj) * 128 + d];
        }
    }

    // ---- phase 2: conv4 + silu via shuffles; xc -> sX + global ----
    for (int dd = 0; dd < 32; ++dd) {
        int d = wq * 32 + dd;                          // uniform
        const float* row = xirow + (size_t)d * 1024;
        float4 wc = *(const float4*)&wconv[d * 4];     // uniform scalar loads
        float v = row[p];                              // coalesced
        float hv = 0.f;
        if (lane < 3 && p0 > 0) hv = row[p0 - 3 + lane];
        float h0 = __shfl(hv, 0), h1 = __shfl(hv, 1), h2 = __shfl(hv, 2);
        float vm1 = __shfl_up(v, 1); if (lane < 1) vm1 = h2;
        float vm2 = __shfl_up(v, 2); if (lane < 2) vm2 = (lane == 1) ? h2 : h1;
        float vm3 = __shfl_up(v, 3); if (lane < 3) vm3 = (lane == 2) ? h2 : (lane == 1) ? h1 : h0;
        float o = bconv[d];
        o += vm3 * wc.x;
        o += vm2 * wc.y;
        o += vm1 * wc.z;
        o += v   * wc.w;
        o = o * sigmoidf_(o);                          // silu
        xcrow[(size_t)d * 1024 + p] = o;               // coalesced global store
        sX[d * 64 + lane] = o;                         // conflict-free (2 lanes/bank)
    }
    __syncthreads();                                   // sX full; sWr replicas ready

    // ---- phase 3: x-proj, K = 128; weights via b64 LDS broadcast ----
    float acc[9];
#pragma unroll
    for (int jj = 0; jj < 9; ++jj) acc[jj] = 0.f;
#pragma unroll 4
    for (int d = 0; d < 128; ++d) {
        float xcv = sX[d * 64 + lane];
        const float* wr = &sWr[(wq * 128 + d) * 10];   // wave-uniform -> broadcast
        float2 w01 = *(const float2*)(wr);
        float2 w23 = *(const float2*)(wr + 2);
        float2 w45 = *(const float2*)(wr + 4);
        float2 w67 = *(const float2*)(wr + 6);
        float  w8  = wr[8];
        acc[0] += w01.x * xcv; acc[1] += w01.y * xcv;
        acc[2] += w23.x * xcv; acc[3] += w23.y * xcv;
        acc[4] += w45.x * xcv; acc[5] += w45.y * xcv;
        acc[6] += w67.x * xcv; acc[7] += w67.y * xcv;
        acc[8] += w8 * xcv;
    }

    float* Bm = ws + O_BM + (size_t)seq * 16384;
    float* Cm = ws + O_CM + (size_t)seq * 16384;
#pragma unroll
    for (int jj = 0; jj < 9; ++jj) {
        int j = j0 + jj;
        if (j < 4) continue;                           // dtp consumed in phase 4
        float t = acc[jj];
        if (j < 20) Bm[(size_t)(j - 4)  * 1024 + p] = t;
        else        Cm[(size_t)(j - 20) * 1024 + p] = t;
    }
    if (wq == 0)
        *(float4*)&sDtp4[lane * 4] = make_float4(acc[0], acc[1], acc[2], acc[3]);
    __syncthreads();                                   // sWr reads done; sDtp4 ready

    // ---- sB5 overlay (dead sWr region): B rows transposed [p_local][s], from registers ----
#pragma unroll
    for (int jj = 0; jj < 9; ++jj) {
        int j = j0 + jj;                               // wave-uniform branch
        if (j >= 4 && j < 20) sB5[lane * 20 + (j - 4)] = acc[jj];
    }

    // ---- phase 4: dt + dx -> global ----
    float* dtg = ws + O_DT + (size_t)seq * 131072;
    float* dxg = ws + O_DX + (size_t)seq * 131072;
    float4 qv = *(const float4*)&sDtp4[lane * 4];
#pragma unroll 4
    for (int dd = 0; dd < 32; ++dd) {
        int d = wq * 32 + dd;                          // uniform
        float4 wv = *(const float4*)&wdt[d * 4];       // uniform scalar loads
        float t = bdt[d] + qv.x*wv.x + qv.y*wv.y + qv.z*wv.z + qv.w*wv.w;
        float dt = softplusf_(t);
        float dx = dt * sX[d * 64 + lane];
        dtg[(size_t)d * 1024 + p] = dt;
        dxg[(size_t)d * 1024 + p] = dx;
    }
    __syncthreads();                                   // dt/dx stores drained; sB5 ready

    // ---- phase 5 (fused k3a): chunk-local scan, h0=0; emit P and E ----
    {
        int dA = tid >> 2;                             // 0..63; pairs with dA+64
        int s05 = (tid & 3) * 4;
        float a2[8];
        {
            float4 a0 = *(const float4*)(alog + dA * 16 + s05);
            float4 a1 = *(const float4*)(alog + (dA + 64) * 16 + s05);
            a2[0] = -fexp2(a0.x * L2E) * L2E; a2[1] = -fexp2(a0.y * L2E) * L2E;
            a2[2] = -fexp2(a0.z * L2E) * L2E; a2[3] = -fexp2(a0.w * L2E) * L2E;
            a2[4] = -fexp2(a1.x * L2E) * L2E; a2[5] = -fexp2(a1.y * L2E) * L2E;
            a2[6] = -fexp2(a1.z * L2E) * L2E; a2[7] = -fexp2(a1.w * L2E) * L2E;
        }
        const float* dtA = ws + O_DT + (size_t)seq * 131072 + (size_t)dA * 1024 + p0;
        const float* dtB = dtA + 65536;                // row dA+64
        const float* dxA = ws + O_DX + (size_t)seq * 131072 + (size_t)dA * 1024 + p0;
        const float* dxB = dxA + 65536;
        float* hp0 = ws + O_HP + (size_t)(seq * 32 + ptile * 2) * 4096;
#pragma unroll
        for (int cc = 0; cc < 2; ++cc) {
            float h[8];
#pragma unroll
            for (int i = 0; i < 8; ++i) h[i] = 0.f;
            float sdtA = 0.f, sdtB = 0.f;
            for (int q4 = 0; q4 < 8; ++q4) {
                float4 t0 = *(const float4*)&dtA[cc * 32 + q4 * 4];
                float4 t1 = *(const float4*)&dtB[cc * 32 + q4 * 4];
                float4 x0 = *(const float4*)&dxA[cc * 32 + q4 * 4];
                float4 x1 = *(const float4*)&dxB[cc * 32 + q4 * 4];
                float t0a[4] = {t0.x, t0.y, t0.z, t0.w};
                float t1a[4] = {t1.x, t1.y, t1.z, t1.w};
                float x0a[4] = {x0.x, x0.y, x0.z, x0.w};
                float x1a[4] = {x1.x, x1.y, x1.z, x1.w};
#pragma unroll
                for (int k = 0; k < 4; ++k) {
                    int li = q4 * 4 + k;
                    float4 Bv = *(const float4*)&sB5[(cc * 32 + li) * 20 + s05];
                    float bv[4] = {Bv.x, Bv.y, Bv.z, Bv.w};
                    float dt0 = t0a[k], dt1 = t1a[k];
                    float dx0 = x0a[k], dx1 = x1a[k];
                    sdtA += dt0; sdtB += dt1;
#pragma unroll
                    for (int ss = 0; ss < 4; ++ss) {
                        float e0 = fexp2(dt0 * a2[ss]);
                        h[ss] = e0 * h[ss] + dx0 * bv[ss];
                        float e1 = fexp2(dt1 * a2[4 + ss]);
                        h[4 + ss] = e1 * h[4 + ss] + dx1 * bv[ss];
                    }
                }
            }
            float* hp = hp0 + (size_t)cc * 4096;
            *(float4*)&hp[dA * 16 + s05] = make_float4(
                fexp2(a2[0] * sdtA), fexp2(a2[1] * sdtA),
                fexp2(a2[2] * sdtA), fexp2(a2[3] * sdtA));
            *(float4*)&hp[(dA + 64) * 16 + s05] = make_float4(
                fexp2(a2[4] * sdtB), fexp2(a2[5] * sdtB),
                fexp2(a2[6] * sdtB), fexp2(a2[7] * sdtB));
            *(float4*)&hp[2048 + dA * 16 + s05]        = make_float4(h[0], h[1], h[2], h[3]);
            *(float4*)&hp[2048 + (dA + 64) * 16 + s05] = make_float4(h[4], h[5], h[6], h[7]);
        }
    }
}

// ---------------- a2 preload for k3cd (d0, d0+1 pairing) ----------------
__device__ __forceinline__ void a2_preload(const float* alog, int d0, int s0, float* a2)
{
    float4 a0 = *(const float4*)(alog + d0 * 16 + s0);
    float4 a1 = *(const float4*)(alog + (d0 + 1) * 16 + s0);
    a2[0] = -fexp2(a0.x * L2E) * L2E; a2[1] = -fexp2(a0.y * L2E) * L2E;
    a2[2] = -fexp2(a0.z * L2E) * L2E; a2[3] = -fexp2(a0.w * L2E) * L2E;
    a2[4] = -fexp2(a1.x * L2E) * L2E; a2[5] = -fexp2(a1.y * L2E) * L2E;
    a2[6] = -fexp2(a1.z * L2E) * L2E; a2[7] = -fexp2(a1.w * L2E) * L2E;
}

// phase B: sequential prefix compose. grid 256 = 32 seq * 8 dgroups, 1 state/thread.
__global__ __launch_bounds__(256) void k3b_compose(float* __restrict__ ws)
{
    int seq = blockIdx.x >> 3, dg = blockIdx.x & 7;
    int idx = dg * 256 + threadIdx.x;
    float h = 0.f;
    float* hpb = ws + O_HP + (size_t)seq * 32 * 4096;
    float P = hpb[idx];
    float E = hpb[2048 + idx];
    for (int c = 0; c < 32; ++c) {
        float* hp = hpb + (size_t)c * 4096;
        float Pn = 0.f, En = 0.f;
        if (c < 31) { Pn = hp[4096 + idx]; En = hp[4096 + 2048 + idx]; }
        hp[idx] = h;
        h = P * h + E;
        P = Pn; E = En;
    }
}

// ================= K3CD: rescan + gate + out-proj + skip =================
// grid 1024 = 32 seq * 32 ch; block 256. LDS 22.5 KB.
__global__ __launch_bounds__(256) void k3cd(
    const float* __restrict__ alog,
    const float* __restrict__ x0, const float* __restrict__ x1,
    const float* __restrict__ x2, const float* __restrict__ x3,
    const float* __restrict__ g1, const float* __restrict__ be1,
    const float* __restrict__ g2, const float* __restrict__ be2,
    const float* __restrict__ g3, const float* __restrict__ be3,
    const float* __restrict__ g4, const float* __restrict__ be4,
    const float* __restrict__ dpar, const float* __restrict__ woutp,
    const float* __restrict__ skipp, float* __restrict__ ws,
    float* __restrict__ out)
{
    __shared__ __align__(16) float sY[128 * 36];     // y, then gated g
    __shared__ __align__(16) float sB[32 * 16];
    __shared__ __align__(16) float sC[32 * 16];
    int bid = blockIdx.x;
    int seq = bid >> 5, ch = bid & 31;
    int branch = seq >> 3, b = seq & 7;
    int lb = ch * 32;
    int tid = threadIdx.x;
    int sq = tid & 3;
    int d0 = (tid >> 2) * 2, s0 = sq * 4;

    float a2[8];
    a2_preload(alog, d0, s0, a2);

    const float* Bmg = ws + O_BM + (size_t)seq * 16384;
    const float* Cmg = ws + O_CM + (size_t)seq * 16384;
    for (int i = tid; i < 512; i += 256) {
        int s = i >> 5, li = i & 31;
        sB[li * 16 + s] = Bmg[(size_t)s * 1024 + lb + li];
        sC[li * 16 + s] = Cmg[(size_t)s * 1024 + lb + li];
    }

    const float* hp = ws + O_HP + (size_t)(seq * 32 + ch) * 4096;
    float4 H0 = *(const float4*)&hp[d0 * 16 + s0];
    float4 H1 = *(const float4*)&hp[(d0 + 1) * 16 + s0];
    float h[8] = {H0.x, H0.y, H0.z, H0.w, H1.x, H1.y, H1.z, H1.w};
    __syncthreads();

    const float* r0t = ws + O_DT + (size_t)seq * 131072 + (size_t)d0 * 1024 + lb;
    const float* r1t = r0t + 1024;
    const float* r0x = ws + O_DX + (size_t)seq * 131072 + (size_t)d0 * 1024 + lb;
    const float* r1x = r0x + 1024;

    // ---- rescan: y into sY (stride 36) ----
    for (int q4 = 0; q4 < 8; ++q4) {
        float4 t0 = *(const float4*)&r0t[q4 * 4];
        float4 t1 = *(const float4*)&r1t[q4 * 4];
        float4 x0v = *(const float4*)&r0x[q4 * 4];
        float4 x1v = *(const float4*)&r1x[q4 * 4];
        float t0a[4] = {t0.x, t0.y, t0.z, t0.w};
        float t1a[4] = {t1.x, t1.y, t1.z, t1.w};
        float x0a[4] = {x0v.x, x0v.y, x0v.z, x0v.w};
        float x1a[4] = {x1v.x, x1v.y, x1v.z, x1v.w};
#pragma unroll
        for (int k = 0; k < 4; ++k) {
            int li = q4 * 4 + k;
            float dt0 = t0a[k], dt1 = t1a[k];
            float dx0 = x0a[k], dx1 = x1a[k];
            float4 Bv = *(const float4*)&sB[li * 16 + s0];
            float4 Cv = *(const float4*)&sC[li * 16 + s0];
            float bv[4] = {Bv.x, Bv.y, Bv.z, Bv.w};
            float cv[4] = {Cv.x, Cv.y, Cv.z, Cv.w};
            float acc0 = 0.f, acc1 = 0.f;
#pragma unroll
            for (int ss = 0; ss < 4; ++ss) {
                float e0 = fexp2(dt0 * a2[ss]);
                h[ss] = e0 * h[ss] + dx0 * bv[ss];
                acc0 += h[ss] * cv[ss];
                float e1 = fexp2(dt1 * a2[4 + ss]);
                h[4 + ss] = e1 * h[4 + ss] + dx1 * bv[ss];
                acc1 += h[4 + ss] * cv[ss];
            }
            acc0 += __shfl_xor(acc0, 1); acc0 += __shfl_xor(acc0, 2);
            acc1 += __shfl_xor(acc1, 1); acc1 += __shfl_xor(acc1, 2);
            if (sq == 0) {
                sY[d0 * 36 + li]       = acc0;
                sY[(d0 + 1) * 36 + li] = acc1;
            }
        }
    }
    __syncthreads();

    // ---- gate in place: g = (y + D*xc) * silu(z) ----
    const float* zzg = ws + O_Z  + (size_t)seq * 131072;
    const float* xcg = ws + O_XC + (size_t)seq * 131072;
    for (int i = tid; i < 4096; i += 256) {
        int d = i >> 5, li = i & 31;
        float zv  = zzg[(size_t)d * 1024 + lb + li];
        float xcv = xcg[(size_t)d * 1024 + lb + li];
        float yv  = sY[d * 36 + li];
        sY[d * 36 + li] = (yv + dpar[d] * xcv) * (zv * sigmoidf_(zv));
    }
    __syncthreads();

    // ---- out-proj GEMM: out[64c][32p] = Wout[64][128] @ g[128][32] ----
    int ctt = tid >> 3;          // c0 = 2*ctt
    int ptq = tid & 7;           // p0 = 4*ptq
    int c0 = ctt * 2;
    const float* w0p = woutp + (size_t)c0 * 128;
    const float* w1p = w0p + 128;
    float acc[2][4];
#pragma unroll
    for (int i = 0; i < 2; ++i)
#pragma unroll
        for (int j = 0; j < 4; ++j) acc[i][j] = 0.f;
    for (int d4 = 0; d4 < 32; ++d4) {
        float4 wa = *(const float4*)&w0p[d4 * 4];
        float4 wb = *(const float4*)&w1p[d4 * 4];
        float waa[4] = {wa.x, wa.y, wa.z, wa.w};
        float wba[4] = {wb.x, wb.y, wb.z, wb.w};
#pragma unroll
        for (int k = 0; k < 4; ++k) {
            int d = d4 * 4 + k;
            float4 gv = *(const float4*)&sY[d * 36 + ptq * 4];
            acc[0][0] += waa[k] * gv.x; acc[0][1] += waa[k] * gv.y;
            acc[0][2] += waa[k] * gv.z; acc[0][3] += waa[k] * gv.w;
            acc[1][0] += wba[k] * gv.x; acc[1][1] += wba[k] * gv.y;
            acc[1][2] += wba[k] * gv.z; acc[1][3] += wba[k] * gv.w;
        }
    }

    // ---- epilogue: + skip * xn ----
    const float* xin = (branch==0)?x0:(branch==1)?x1:(branch==2)?x2:x3;
    const float* gam = (branch==0)?g1:(branch==1)?g2:(branch==2)?g3:g4;
    const float* bet = (branch==0)?be1:(branch==1)?be2:(branch==2)?be3:be4;
    const float* xb = xin + (size_t)b * 65536;
    int pp = lb + ptq * 4;
    float skipv = skipp[0];
    float4 m4 = *(const float4*)&ws[O_M  + (size_t)seq * 1024 + pp];
    float4 r4 = *(const float4*)&ws[O_RS + (size_t)seq * 1024 + pp];
    float mm[4] = {m4.x, m4.y, m4.z, m4.w};
    float rr[4] = {r4.x, r4.y, r4.z, r4.w};
#pragma unroll
    for (int ci = 0; ci < 2; ++ci) {
        int c = c0 + ci;
        float4 xv = *(const float4*)&xb[(size_t)c * 1024 + pp];
        float xvv[4] = {xv.x, xv.y, xv.z, xv.w};
        float gc = gam[c], bc = bet[c];
        float o[4];
#pragma unroll
        for (int pi = 0; pi < 4; ++pi) {
            float xn = (xvv[pi] - mm[pi]) * rr[pi] * gc + bc;
            o[pi] = acc[ci][pi] + skipv * xn;
        }
        *(float4*)&out[((size_t)b * 256 + branch * 64 + c) * 1024 + pp] =
            make_float4(o[0], o[1], o[2], o[3]);
    }
}

// ---------------- launch ----------------
extern "C" void kernel_launch(void* const* d_in, const int* in_sizes, int n_in,
                              void* d_out, int out_size, void* d_ws, size_t ws_size,
                              hipStream_t stream) {
    float* ws = (float*)d_ws;
    auto f = [&](int i) { return (const float*)d_in[i]; };
    hipLaunchKernelGGL(k1_ln_inproj, dim3(512), dim3(256), 0, stream,
        f(0), f(1), f(2), f(3), f(13),
        f(4), f(5), f(6), f(7), f(8), f(9), f(10), f(11), ws);
    hipLaunchKernelGGL(k2_conv_proj, dim3(512), dim3(256), 0, stream,
        f(14), f(15), f(16), f(17), f(18), f(19), ws);
    hipLaunchKernelGGL(k3b_compose, dim3(256), dim3(256), 0, stream, ws);
    hipLaunchKernelGGL(k3cd, dim3(1024), dim3(256), 0, stream,
        f(19),
        f(0), f(1), f(2), f(3),
        f(4), f(5), f(6), f(7), f(8), f(9), f(10), f(11),
        f(20), f(21), f(12), ws, (float*)d_out);
}

// Round 15
// 201.446 us; speedup vs baseline: 1.0703x; 1.0169x over previous
//
#include <hip/hip_runtime.h>
#include <hip/hip_bf16.h>

#define L2E 1.4426950408889634f
#define LN2 0.6931471805599453f

__device__ __forceinline__ float fexp2(float x) { return __builtin_amdgcn_exp2f(x); }
__device__ __forceinline__ float flog2(float x) { return __builtin_amdgcn_logf(x); }
__device__ __forceinline__ int uniform(int x) { return __builtin_amdgcn_readfirstlane(x); }
__device__ __forceinline__ float sigmoidf_(float v) { return 1.f / (1.f + fexp2(-v * L2E)); }
__device__ __forceinline__ float softplusf_(float t) {
    return (t > 20.f) ? t : LN2 * flog2(1.f + fexp2(t * L2E));
}

// ---------------- workspace layout (floats), total 26,411,008 = 105.6 MB (pool = 256 MiB) ----
constexpr size_t O_M   = 0;          // [32][1024] LN mean
constexpr size_t O_RS  = 32768;      // [32][1024] LN rstd
constexpr size_t O_G   = 65536;      // [32][128][1024] xi
constexpr size_t O_Z   = 4259840;    // [32][128][1024] z
constexpr size_t O_XC  = 8454144;    // [32][128][1024] conv+silu out
constexpr size_t O_BM  = 12648448;   // [32][16][1024]
constexpr size_t O_CM  = 13172736;   // [32][16][1024]
constexpr size_t O_HP  = 13828096;   // [32][32][2][2048]: per-chunk P (→h_init) and E
constexpr size_t O_DT  = 18022400;   // [32][128][1024] dt (post-softplus)
constexpr size_t O_DX  = 22216704;   // [32][128][1024] dx = dt*xc

// ================= K1: LN + in-proj GEMM W[256,64] @ XN[64,1024], jb-merged =================
// grid 512 = 32 seq * 16 pb; block 256 (16 jt x 16 pt).
__global__ __launch_bounds__(256) void k1_ln_inproj(
    const float* __restrict__ x0, const float* __restrict__ x1,
    const float* __restrict__ x2, const float* __restrict__ x3,
    const float* __restrict__ win,
    const float* __restrict__ g1, const float* __restrict__ be1,
    const float* __restrict__ g2, const float* __restrict__ be2,
    const float* __restrict__ g3, const float* __restrict__ be3,
    const float* __restrict__ g4, const float* __restrict__ be4,
    float* __restrict__ ws)
{
    __shared__ float sX[64 * 68];
    __shared__ float sW[64 * 68];
    __shared__ float sM[64], sR[64];
    int bid = blockIdx.x;
    int seq = bid >> 4, pb = bid & 15;
    int branch = seq >> 3, b = seq & 7;
    int tid = threadIdx.x;
    int lane = tid & 63;
    int wq = uniform(tid >> 6);
    const float* xin = (branch==0)?x0:(branch==1)?x1:(branch==2)?x2:x3;
    const float* gam = (branch==0)?g1:(branch==1)?g2:(branch==2)?g3:g4;
    const float* bet = (branch==0)?be1:(branch==1)?be2:(branch==2)?be3:be4;
    const float* xb = xin + (size_t)b * 65536;

#pragma unroll
    for (int r = 0; r < 16; ++r) {
        int row = r * 4 + wq;                         // uniform per wave
        sX[row * 68 + lane] = xb[(size_t)row * 1024 + pb * 64 + lane];
    }
    __syncthreads();
    if (tid < 64) {
        float sum = 0.f, sq = 0.f;
#pragma unroll
        for (int c = 0; c < 64; ++c) {
            float v = sX[c * 68 + tid];
            sum += v; sq += v * v;
        }
        float mean = sum * (1.f/64.f);
        float var  = sq * (1.f/64.f) - mean * mean;
        float rs   = rsqrtf(var + 1e-5f);
        sM[tid] = mean; sR[tid] = rs;
        ws[O_M  + (size_t)seq * 1024 + pb * 64 + tid] = mean;
        ws[O_RS + (size_t)seq * 1024 + pb * 64 + tid] = rs;
    }
    __syncthreads();
#pragma unroll
    for (int r = 0; r < 16; ++r) {
        int c = r * 4 + wq;
        float v = sX[c * 68 + lane];
        sX[c * 68 + lane] = (v - sM[lane]) * sR[lane] * gam[c] + bet[c];
    }
    __syncthreads();

    int jt = tid >> 4, pt = tid & 15;
    int p0 = pb * 64 + pt * 4;
    float* xi = ws + O_G + (size_t)seq * 131072;
    float* zz = ws + O_Z + (size_t)seq * 131072;

    for (int jb = 0; jb < 4; ++jb) {
#pragma unroll
        for (int r = 0; r < 16; ++r) {
            int row = r * 4 + wq;
            sW[lane * 68 + row] = win[(size_t)(jb * 64 + row) * 64 + lane];
        }
        __syncthreads();
        float acc[4][4];
#pragma unroll
        for (int i = 0; i < 4; ++i)
#pragma unroll
            for (int j = 0; j < 4; ++j) acc[i][j] = 0.f;
        for (int c = 0; c < 64; ++c) {
            float4 wv = *(const float4*)&sW[c * 68 + jt * 4];
            float4 xv = *(const float4*)&sX[c * 68 + pt * 4];
            float w[4] = {wv.x, wv.y, wv.z, wv.w};
            float x[4] = {xv.x, xv.y, xv.z, xv.w};
#pragma unroll
            for (int i = 0; i < 4; ++i)
#pragma unroll
                for (int j = 0; j < 4; ++j) acc[i][j] += w[i] * x[j];
        }
#pragma unroll
        for (int ji = 0; ji < 4; ++ji) {
            int j = jb * 64 + jt * 4 + ji;
            float4 v = make_float4(acc[ji][0], acc[ji][1], acc[ji][2], acc[ji][3]);
            if (j < 128) *(float4*)&xi[(size_t)j * 1024 + p0] = v;
            else         *(float4*)&zz[(size_t)(j - 128) * 1024 + p0] = v;
        }
        __syncthreads();
    }
}

// ================= K2: conv+silu + x-proj + dt/dx + chunk-local scan (fused, 8 waves) =====
// grid 512 = 32 seq * 16 ptile; block 512 = 8 waves x 64 p-lanes.
// R11: R10 showed occupancy is GRID-capped (512 blocks = 2/CU), so LDS cuts couldn't help.
// 512-thread blocks double waves/CU (8->16) and halve per-thread serial work:
//   conv 16 rows/wave; x-proj j's split 5,5,5,5,4,4,4,4 over 8 waves; phase-5 one d/thread.
__global__ __launch_bounds__(512) void k2_conv_proj(
    const float* __restrict__ wconv, const float* __restrict__ bconv,
    const float* __restrict__ wxp,
    const float* __restrict__ wdt, const float* __restrict__ bdt,
    const float* __restrict__ alog,
    float* __restrict__ ws)
{
    __shared__ __align__(16) float sX[128 * 64];      // xc [d][p_local]
    __shared__ __align__(16) float sWr[8 * 128 * 6];  // weight replicas; -> sB5 after ph3
    __shared__ __align__(16) float sDtp4[64 * 4];
    float* sB5 = sWr;                                 // [64][20] B rows, overlay

    int bid = blockIdx.x;
    int seq = bid >> 4, ptile = bid & 15;
    int tid = threadIdx.x;
    int lane = tid & 63;
    int wq = uniform(tid >> 6);                       // 0..7
    int p0 = ptile * 64;
    int p  = p0 + lane;
    int jcount = (wq < 4) ? 5 : 4;                    // wave-uniform
    int j0 = (wq < 4) ? wq * 5 : 20 + (wq - 4) * 4;

    const float* xirow = ws + O_G  + (size_t)seq * 131072;
    float*       xcrow = ws + O_XC + (size_t)seq * 131072;

    // ---- phase 1: stage weight replicas (stride 6) ----
#pragma unroll
    for (int jj = 0; jj < 5; ++jj) {
        if (jj < jcount) {
#pragma unroll
            for (int half = 0; half < 2; ++half) {
                int d = half * 64 + lane;
                sWr[(wq * 128 + d) * 6 + jj] = wxp[(size_t)(j0 + jj) * 128 + d];
            }
        }
    }

    // ---- phase 2: conv4 + silu via shuffles; xc -> sX + global (16 rows/wave) ----
    for (int dd = 0; dd < 16; ++dd) {
        int d = wq * 16 + dd;                          // uniform
        const float* row = xirow + (size_t)d * 1024;
        float4 wc = *(const float4*)&wconv[d * 4];     // uniform scalar loads
        float v = row[p];                              // coalesced
        float hv = 0.f;
        if (lane < 3 && p0 > 0) hv = row[p0 - 3 + lane];
        float h0 = __shfl(hv, 0), h1 = __shfl(hv, 1), h2 = __shfl(hv, 2);
        float vm1 = __shfl_up(v, 1); if (lane < 1) vm1 = h2;
        float vm2 = __shfl_up(v, 2); if (lane < 2) vm2 = (lane == 1) ? h2 : h1;
        float vm3 = __shfl_up(v, 3); if (lane < 3) vm3 = (lane == 2) ? h2 : (lane == 1) ? h1 : h0;
        float o = bconv[d];
        o += vm3 * wc.x;
        o += vm2 * wc.y;
        o += vm1 * wc.z;
        o += v   * wc.w;
        o = o * sigmoidf_(o);                          // silu
        xcrow[(size_t)d * 1024 + p] = o;               // coalesced global store
        sX[d * 64 + lane] = o;                         // conflict-free (2 lanes/bank)
    }
    __syncthreads();                                   // sX full; sWr replicas ready

    // ---- phase 3: x-proj, K = 128; weights via LDS broadcast ----
    float acc[5];
#pragma unroll
    for (int jj = 0; jj < 5; ++jj) acc[jj] = 0.f;
#pragma unroll 4
    for (int d = 0; d < 128; ++d) {
        float xcv = sX[d * 64 + lane];
        const float* wr = &sWr[(wq * 128 + d) * 6];    // wave-uniform -> broadcast
        float2 wA = *(const float2*)(wr);
        float2 wB = *(const float2*)(wr + 2);
        acc[0] += wA.x * xcv; acc[1] += wA.y * xcv;
        acc[2] += wB.x * xcv; acc[3] += wB.y * xcv;
        if (wq < 4) acc[4] += wr[4] * xcv;             // wave-uniform branch
    }

    float* Bm = ws + O_BM + (size_t)seq * 16384;
    float* Cm = ws + O_CM + (size_t)seq * 16384;
#pragma unroll
    for (int jj = 0; jj < 5; ++jj) {
        if (jj < jcount) {
            int j = j0 + jj;
            if (j < 4) continue;                       // dtp consumed in phase 4 (wq0 j0-3)
            float t = acc[jj];
            if (j < 20) Bm[(size_t)(j - 4)  * 1024 + p] = t;
            else        Cm[(size_t)(j - 20) * 1024 + p] = t;
        }
    }
    if (wq == 0)
        *(float4*)&sDtp4[lane * 4] = make_float4(acc[0], acc[1], acc[2], acc[3]);
    __syncthreads();                                   // sWr reads done; sDtp4 ready

    // ---- sB5 overlay (dead sWr region): B rows [p_local][s], from registers ----
#pragma unroll
    for (int jj = 0; jj < 5; ++jj) {
        if (jj < jcount) {
            int j = j0 + jj;                           // wave-uniform per jj
            if (j >= 4 && j < 20) sB5[lane * 20 + (j - 4)] = acc[jj];
        }
    }

    // ---- phase 4: dt + dx -> global (16 rows/wave) ----
    float* dtg = ws + O_DT + (size_t)seq * 131072;
    float* dxg = ws + O_DX + (size_t)seq * 131072;
    float4 qv = *(const float4*)&sDtp4[lane * 4];
#pragma unroll 4
    for (int dd = 0; dd < 16; ++dd) {
        int d = wq * 16 + dd;                          // uniform
        float4 wv = *(const float4*)&wdt[d * 4];       // uniform scalar loads
        float t = bdt[d] + qv.x*wv.x + qv.y*wv.y + qv.z*wv.z + qv.w*wv.w;
        float dt = softplusf_(t);
        float dx = dt * sX[d * 64 + lane];
        dtg[(size_t)d * 1024 + p] = dt;
        dxg[(size_t)d * 1024 + p] = dx;
    }
    __syncthreads();                                   // dt/dx stores drained; sB5 ready

    // ---- phase 5 (fused k3a): chunk-local scan, ONE d-row per thread, 4 states ----
    {
        int dA = tid >> 2;                             // 0..127
        int s05 = (tid & 3) * 4;
        float a2[4];
        {
            float4 a0 = *(const float4*)(alog + dA * 16 + s05);
            a2[0] = -fexp2(a0.x * L2E) * L2E; a2[1] = -fexp2(a0.y * L2E) * L2E;
            a2[2] = -fexp2(a0.z * L2E) * L2E; a2[3] = -fexp2(a0.w * L2E) * L2E;
        }
        const float* dtA = ws + O_DT + (size_t)seq * 131072 + (size_t)dA * 1024 + p0;
        const float* dxA = ws + O_DX + (size_t)seq * 131072 + (size_t)dA * 1024 + p0;
        float* hp0 = ws + O_HP + (size_t)(seq * 32 + ptile * 2) * 4096;
#pragma unroll
        for (int cc = 0; cc < 2; ++cc) {
            float h[4];
#pragma unroll
            for (int i = 0; i < 4; ++i) h[i] = 0.f;
            float sdtA = 0.f;
            for (int q4 = 0; q4 < 8; ++q4) {
                float4 t0 = *(const float4*)&dtA[cc * 32 + q4 * 4];
                float4 x0 = *(const float4*)&dxA[cc * 32 + q4 * 4];
                float t0a[4] = {t0.x, t0.y, t0.z, t0.w};
                float x0a[4] = {x0.x, x0.y, x0.z, x0.w};
#pragma unroll
                for (int k = 0; k < 4; ++k) {
                    int li = q4 * 4 + k;
                    float4 Bv = *(const float4*)&sB5[(cc * 32 + li) * 20 + s05];
                    float bv[4] = {Bv.x, Bv.y, Bv.z, Bv.w};
                    float dt0 = t0a[k];
                    float dx0 = x0a[k];
                    sdtA += dt0;
#pragma unroll
                    for (int ss = 0; ss < 4; ++ss) {
                        float e0 = fexp2(dt0 * a2[ss]);
                        h[ss] = e0 * h[ss] + dx0 * bv[ss];
                    }
                }
            }
            float* hp = hp0 + (size_t)cc * 4096;
            *(float4*)&hp[dA * 16 + s05] = make_float4(
                fexp2(a2[0] * sdtA), fexp2(a2[1] * sdtA),
                fexp2(a2[2] * sdtA), fexp2(a2[3] * sdtA));
            *(float4*)&hp[2048 + dA * 16 + s05] = make_float4(h[0], h[1], h[2], h[3]);
        }
    }
}

// ---------------- a2 preload for k3cd (d0, d0+1 pairing) ----------------
__device__ __forceinline__ void a2_preload(const float* alog, int d0, int s0, float* a2)
{
    float4 a0 = *(const float4*)(alog + d0 * 16 + s0);
    float4 a1 = *(const float4*)(alog + (d0 + 1) * 16 + s0);
    a2[0] = -fexp2(a0.x * L2E) * L2E; a2[1] = -fexp2(a0.y * L2E) * L2E;
    a2[2] = -fexp2(a0.z * L2E) * L2E; a2[3] = -fexp2(a0.w * L2E) * L2E;
    a2[4] = -fexp2(a1.x * L2E) * L2E; a2[5] = -fexp2(a1.y * L2E) * L2E;
    a2[6] = -fexp2(a1.z * L2E) * L2E; a2[7] = -fexp2(a1.w * L2E) * L2E;
}

// phase B: sequential prefix compose. grid 256 = 32 seq * 8 dgroups, 1 state/thread.
__global__ __launch_bounds__(256) void k3b_compose(float* __restrict__ ws)
{
    int seq = blockIdx.x >> 3, dg = blockIdx.x & 7;
    int idx = dg * 256 + threadIdx.x;
    float h = 0.f;
    float* hpb = ws + O_HP + (size_t)seq * 32 * 4096;
    float P = hpb[idx];
    float E = hpb[2048 + idx];
    for (int c = 0; c < 32; ++c) {
        float* hp = hpb + (size_t)c * 4096;
        float Pn = 0.f, En = 0.f;
        if (c < 31) { Pn = hp[4096 + idx]; En = hp[4096 + 2048 + idx]; }
        hp[idx] = h;
        h = P * h + E;
        P = Pn; E = En;
    }
}

// ================= K3CD: rescan + gate + out-proj + skip =================
// grid 1024 = 32 seq * 32 ch; block 256. LDS 22.5 KB.
__global__ __launch_bounds__(256) void k3cd(
    const float* __restrict__ alog,
    const float* __restrict__ x0, const float* __restrict__ x1,
    const float* __restrict__ x2, const float* __restrict__ x3,
    const float* __restrict__ g1, const float* __restrict__ be1,
    const float* __restrict__ g2, const float* __restrict__ be2,
    const float* __restrict__ g3, const float* __restrict__ be3,
    const float* __restrict__ g4, const float* __restrict__ be4,
    const float* __restrict__ dpar, const float* __restrict__ woutp,
    const float* __restrict__ skipp, float* __restrict__ ws,
    float* __restrict__ out)
{
    __shared__ __align__(16) float sY[128 * 36];     // y, then gated g
    __shared__ __align__(16) float sB[32 * 16];
    __shared__ __align__(16) float sC[32 * 16];
    int bid = blockIdx.x;
    int seq = bid >> 5, ch = bid & 31;
    int branch = seq >> 3, b = seq & 7;
    int lb = ch * 32;
    int tid = threadIdx.x;
    int sq = tid & 3;
    int d0 = (tid >> 2) * 2, s0 = sq * 4;

    float a2[8];
    a2_preload(alog, d0, s0, a2);

    const float* Bmg = ws + O_BM + (size_t)seq * 16384;
    const float* Cmg = ws + O_CM + (size_t)seq * 16384;
    for (int i = tid; i < 512; i += 256) {
        int s = i >> 5, li = i & 31;
        sB[li * 16 + s] = Bmg[(size_t)s * 1024 + lb + li];
        sC[li * 16 + s] = Cmg[(size_t)s * 1024 + lb + li];
    }

    const float* hp = ws + O_HP + (size_t)(seq * 32 + ch) * 4096;
    float4 H0 = *(const float4*)&hp[d0 * 16 + s0];
    float4 H1 = *(const float4*)&hp[(d0 + 1) * 16 + s0];
    float h[8] = {H0.x, H0.y, H0.z, H0.w, H1.x, H1.y, H1.z, H1.w};
    __syncthreads();

    const float* r0t = ws + O_DT + (size_t)seq * 131072 + (size_t)d0 * 1024 + lb;
    const float* r1t = r0t + 1024;
    const float* r0x = ws + O_DX + (size_t)seq * 131072 + (size_t)d0 * 1024 + lb;
    const float* r1x = r0x + 1024;

    // ---- rescan: y into sY (stride 36) ----
    for (int q4 = 0; q4 < 8; ++q4) {
        float4 t0 = *(const float4*)&r0t[q4 * 4];
        float4 t1 = *(const float4*)&r1t[q4 * 4];
        float4 x0v = *(const float4*)&r0x[q4 * 4];
        float4 x1v = *(const float4*)&r1x[q4 * 4];
        float t0a[4] = {t0.x, t0.y, t0.z, t0.w};
        float t1a[4] = {t1.x, t1.y, t1.z, t1.w};
        float x0a[4] = {x0v.x, x0v.y, x0v.z, x0v.w};
        float x1a[4] = {x1v.x, x1v.y, x1v.z, x1v.w};
#pragma unroll
        for (int k = 0; k < 4; ++k) {
            int li = q4 * 4 + k;
            float dt0 = t0a[k], dt1 = t1a[k];
            float dx0 = x0a[k], dx1 = x1a[k];
            float4 Bv = *(const float4*)&sB[li * 16 + s0];
            float4 Cv = *(const float4*)&sC[li * 16 + s0];
            float bv[4] = {Bv.x, Bv.y, Bv.z, Bv.w};
            float cv[4] = {Cv.x, Cv.y, Cv.z, Cv.w};
            float acc0 = 0.f, acc1 = 0.f;
#pragma unroll
            for (int ss = 0; ss < 4; ++ss) {
                float e0 = fexp2(dt0 * a2[ss]);
                h[ss] = e0 * h[ss] + dx0 * bv[ss];
                acc0 += h[ss] * cv[ss];
                float e1 = fexp2(dt1 * a2[4 + ss]);
                h[4 + ss] = e1 * h[4 + ss] + dx1 * bv[ss];
                acc1 += h[4 + ss] * cv[ss];
            }
            acc0 += __shfl_xor(acc0, 1); acc0 += __shfl_xor(acc0, 2);
            acc1 += __shfl_xor(acc1, 1); acc1 += __shfl_xor(acc1, 2);
            if (sq == 0) {
                sY[d0 * 36 + li]       = acc0;
                sY[(d0 + 1) * 36 + li] = acc1;
            }
        }
    }
    __syncthreads();

    // ---- gate in place: g = (y + D*xc) * silu(z) ----
    const float* zzg = ws + O_Z  + (size_t)seq * 131072;
    const float* xcg = ws + O_XC + (size_t)seq * 131072;
    for (int i = tid; i < 4096; i += 256) {
        int d = i >> 5, li = i & 31;
        float zv  = zzg[(size_t)d * 1024 + lb + li];
        float xcv = xcg[(size_t)d * 1024 + lb + li];
        float yv  = sY[d * 36 + li];
        sY[d * 36 + li] = (yv + dpar[d] * xcv) * (zv * sigmoidf_(zv));
    }
    __syncthreads();

    // ---- out-proj GEMM: out[64c][32p] = Wout[64][128] @ g[128][32] ----
    int ctt = tid >> 3;          // c0 = 2*ctt
    int ptq = tid & 7;           // p0 = 4*ptq
    int c0 = ctt * 2;
    const float* w0p = woutp + (size_t)c0 * 128;
    const float* w1p = w0p + 128;
    float acc[2][4];
#pragma unroll
    for (int i = 0; i < 2; ++i)
#pragma unroll
        for (int j = 0; j < 4; ++j) acc[i][j] = 0.f;
    for (int d4 = 0; d4 < 32; ++d4) {
        float4 wa = *(const float4*)&w0p[d4 * 4];
        float4 wb = *(const float4*)&w1p[d4 * 4];
        float waa[4] = {wa.x, wa.y, wa.z, wa.w};
        float wba[4] = {wb.x, wb.y, wb.z, wb.w};
#pragma unroll
        for (int k = 0; k < 4; ++k) {
            int d = d4 * 4 + k;
            float4 gv = *(const float4*)&sY[d * 36 + ptq * 4];
            acc[0][0] += waa[k] * gv.x; acc[0][1] += waa[k] * gv.y;
            acc[0][2] += waa[k] * gv.z; acc[0][3] += waa[k] * gv.w;
            acc[1][0] += wba[k] * gv.x; acc[1][1] += wba[k] * gv.y;
            acc[1][2] += wba[k] * gv.z; acc[1][3] += wba[k] * gv.w;
        }
    }

    // ---- epilogue: + skip * xn ----
    const float* xin = (branch==0)?x0:(branch==1)?x1:(branch==2)?x2:x3;
    const float* gam = (branch==0)?g1:(branch==1)?g2:(branch==2)?g3:g4;
    const float* bet = (branch==0)?be1:(branch==1)?be2:(branch==2)?be3:be4;
    const float* xb = xin + (size_t)b * 65536;
    int pp = lb + ptq * 4;
    float skipv = skipp[0];
    float4 m4 = *(const float4*)&ws[O_M  + (size_t)seq * 1024 + pp];
    float4 r4 = *(const float4*)&ws[O_RS + (size_t)seq * 1024 + pp];
    float mm[4] = {m4.x, m4.y, m4.z, m4.w};
    float rr[4] = {r4.x, r4.y, r4.z, r4.w};
#pragma unroll
    for (int ci = 0; ci < 2; ++ci) {
        int c = c0 + ci;
        float4 xv = *(const float4*)&xb[(size_t)c * 1024 + pp];
        float xvv[4] = {xv.x, xv.y, xv.z, xv.w};
        float gc = gam[c], bc = bet[c];
        float o[4];
#pragma unroll
        for (int pi = 0; pi < 4; ++pi) {
            float xn = (xvv[pi] - mm[pi]) * rr[pi] * gc + bc;
            o[pi] = acc[ci][pi] + skipv * xn;
        }
        *(float4*)&out[((size_t)b * 256 + branch * 64 + c) * 1024 + pp] =
            make_float4(o[0], o[1], o[2], o[3]);
    }
}

// ---------------- launch ----------------
extern "C" void kernel_launch(void* const* d_in, const int* in_sizes, int n_in,
                              void* d_out, int out_size, void* d_ws, size_t ws_size,
                              hipStream_t stream) {
    float* ws = (float*)d_ws;
    auto f = [&](int i) { return (const float*)d_in[i]; };
    hipLaunchKernelGGL(k1_ln_inproj, dim3(512), dim3(256), 0, stream,
        f(0), f(1), f(2), f(3), f(13),
        f(4), f(5), f(6), f(7), f(8), f(9), f(10), f(11), ws);
    hipLaunchKernelGGL(k2_conv_proj, dim3(512), dim3(512), 0, stream,
        f(14), f(15), f(16), f(17), f(18), f(19), ws);
    hipLaunchKernelGGL(k3b_compose, dim3(256), dim3(256), 0, stream, ws);
    hipLaunchKernelGGL(k3cd, dim3(1024), dim3(256), 0, stream,
        f(19),
        f(0), f(1), f(2), f(3),
        f(4), f(5), f(6), f(7), f(8), f(9), f(10), f(11),
        f(20), f(21), f(12), ws, (float*)d_out);
}

// Round 20
// 200.193 us; speedup vs baseline: 1.0770x; 1.0063x over previous
//
#include <hip/hip_runtime.h>
#include <hip/hip_bf16.h>

#define L2E 1.4426950408889634f
#define LN2 0.6931471805599453f

__device__ __forceinline__ float fexp2(float x) { return __builtin_amdgcn_exp2f(x); }
__device__ __forceinline__ float flog2(float x) { return __builtin_amdgcn_logf(x); }
__device__ __forceinline__ int uniform(int x) { return __builtin_amdgcn_readfirstlane(x); }
__device__ __forceinline__ float sigmoidf_(float v) { return 1.f / (1.f + fexp2(-v * L2E)); }
__device__ __forceinline__ float softplusf_(float t) {
    return (t > 20.f) ? t : LN2 * flog2(1.f + fexp2(t * L2E));
}

// ---------------- workspace layout (floats), total 26,411,008 = 105.6 MB (pool = 256 MiB) ----
constexpr size_t O_M   = 0;          // [32][1024] LN mean
constexpr size_t O_RS  = 32768;      // [32][1024] LN rstd
constexpr size_t O_G   = 65536;      // [32][128][1024] xi
constexpr size_t O_Z   = 4259840;    // [32][128][1024] z
constexpr size_t O_XC  = 8454144;    // [32][128][1024] conv+silu out
constexpr size_t O_BM  = 12648448;   // [32][16][1024]
constexpr size_t O_CM  = 13172736;   // [32][16][1024]
constexpr size_t O_HP  = 13828096;   // [32][32][2][2048]: per-chunk P (→h_init) and E
constexpr size_t O_DT  = 18022400;   // [32][128][1024] dt (post-softplus)
constexpr size_t O_DX  = 22216704;   // [32][128][1024] dx = dt*xc

// ================= K1: LN + in-proj GEMM W[256,64] @ XN[64,1024], jb-merged =================
// grid 512 = 32 seq * 16 pb; block 256 (16 jt x 16 pt).
__global__ __launch_bounds__(256) void k1_ln_inproj(
    const float* __restrict__ x0, const float* __restrict__ x1,
    const float* __restrict__ x2, const float* __restrict__ x3,
    const float* __restrict__ win,
    const float* __restrict__ g1, const float* __restrict__ be1,
    const float* __restrict__ g2, const float* __restrict__ be2,
    const float* __restrict__ g3, const float* __restrict__ be3,
    const float* __restrict__ g4, const float* __restrict__ be4,
    float* __restrict__ ws)
{
    __shared__ float sX[64 * 68];
    __shared__ float sW[64 * 68];
    __shared__ float sM[64], sR[64];
    int bid = blockIdx.x;
    int seq = bid >> 4, pb = bid & 15;
    int branch = seq >> 3, b = seq & 7;
    int tid = threadIdx.x;
    int lane = tid & 63;
    int wq = uniform(tid >> 6);
    const float* xin = (branch==0)?x0:(branch==1)?x1:(branch==2)?x2:x3;
    const float* gam = (branch==0)?g1:(branch==1)?g2:(branch==2)?g3:g4;
    const float* bet = (branch==0)?be1:(branch==1)?be2:(branch==2)?be3:be4;
    const float* xb = xin + (size_t)b * 65536;

#pragma unroll
    for (int r = 0; r < 16; ++r) {
        int row = r * 4 + wq;                         // uniform per wave
        sX[row * 68 + lane] = xb[(size_t)row * 1024 + pb * 64 + lane];
    }
    __syncthreads();
    if (tid < 64) {
        float sum = 0.f, sq = 0.f;
#pragma unroll
        for (int c = 0; c < 64; ++c) {
            float v = sX[c * 68 + tid];
            sum += v; sq += v * v;
        }
        float mean = sum * (1.f/64.f);
        float var  = sq * (1.f/64.f) - mean * mean;
        float rs   = rsqrtf(var + 1e-5f);
        sM[tid] = mean; sR[tid] = rs;
        ws[O_M  + (size_t)seq * 1024 + pb * 64 + tid] = mean;
        ws[O_RS + (size_t)seq * 1024 + pb * 64 + tid] = rs;
    }
    __syncthreads();
#pragma unroll
    for (int r = 0; r < 16; ++r) {
        int c = r * 4 + wq;
        float v = sX[c * 68 + lane];
        sX[c * 68 + lane] = (v - sM[lane]) * sR[lane] * gam[c] + bet[c];
    }
    __syncthreads();

    int jt = tid >> 4, pt = tid & 15;
    int p0 = pb * 64 + pt * 4;
    float* xi = ws + O_G + (size_t)seq * 131072;
    float* zz = ws + O_Z + (size_t)seq * 131072;

    for (int jb = 0; jb < 4; ++jb) {
#pragma unroll
        for (int r = 0; r < 16; ++r) {
            int row = r * 4 + wq;
            sW[lane * 68 + row] = win[(size_t)(jb * 64 + row) * 64 + lane];
        }
        __syncthreads();
        float acc[4][4];
#pragma unroll
        for (int i = 0; i < 4; ++i)
#pragma unroll
            for (int j = 0; j < 4; ++j) acc[i][j] = 0.f;
        for (int c = 0; c < 64; ++c) {
            float4 wv = *(const float4*)&sW[c * 68 + jt * 4];
            float4 xv = *(const float4*)&sX[c * 68 + pt * 4];
            float w[4] = {wv.x, wv.y, wv.z, wv.w};
            float x[4] = {xv.x, xv.y, xv.z, xv.w};
#pragma unroll
            for (int i = 0; i < 4; ++i)
#pragma unroll
                for (int j = 0; j < 4; ++j) acc[i][j] += w[i] * x[j];
        }
#pragma unroll
        for (int ji = 0; ji < 4; ++ji) {
            int j = jb * 64 + jt * 4 + ji;
            float4 v = make_float4(acc[ji][0], acc[ji][1], acc[ji][2], acc[ji][3]);
            if (j < 128) *(float4*)&xi[(size_t)j * 1024 + p0] = v;
            else         *(float4*)&zz[(size_t)(j - 128) * 1024 + p0] = v;
        }
        __syncthreads();
    }
}

// ================= K2: conv+silu + x-proj + dt/dx + chunk-local scan (fused, 8 waves) =====
// grid 512 = 32 seq * 16 ptile; block 512 = 8 waves x 64 p-lanes.
// R20: reverted to the R15-verified form (phase 5 reads dt/dx from global). The R16 LDS
// handoff (uA overlay + in-place sX) failed the replay-determinism check (absmax 2.83
// post-timing) — raced intermittently; reverted per rigor discipline.
__global__ __launch_bounds__(512) void k2_conv_proj(
    const float* __restrict__ wconv, const float* __restrict__ bconv,
    const float* __restrict__ wxp,
    const float* __restrict__ wdt, const float* __restrict__ bdt,
    const float* __restrict__ alog,
    float* __restrict__ ws)
{
    __shared__ __align__(16) float sX[128 * 64];      // xc [d][p_local]
    __shared__ __align__(16) float sWr[8 * 128 * 6];  // weight replicas; -> sB5 after ph3
    __shared__ __align__(16) float sDtp4[64 * 4];
    float* sB5 = sWr;                                 // [64][20] B rows, overlay

    int bid = blockIdx.x;
    int seq = bid >> 4, ptile = bid & 15;
    int tid = threadIdx.x;
    int lane = tid & 63;
    int wq = uniform(tid >> 6);                       // 0..7
    int p0 = ptile * 64;
    int p  = p0 + lane;
    int jcount = (wq < 4) ? 5 : 4;                    // wave-uniform
    int j0 = (wq < 4) ? wq * 5 : 20 + (wq - 4) * 4;

    const float* xirow = ws + O_G  + (size_t)seq * 131072;
    float*       xcrow = ws + O_XC + (size_t)seq * 131072;

    // ---- phase 1: stage weight replicas (stride 6) ----
#pragma unroll
    for (int jj = 0; jj < 5; ++jj) {
        if (jj < jcount) {
#pragma unroll
            for (int half = 0; half < 2; ++half) {
                int d = half * 64 + lane;
                sWr[(wq * 128 + d) * 6 + jj] = wxp[(size_t)(j0 + jj) * 128 + d];
            }
        }
    }

    // ---- phase 2: conv4 + silu via shuffles; xc -> sX + global (16 rows/wave) ----
    for (int dd = 0; dd < 16; ++dd) {
        int d = wq * 16 + dd;                          // uniform
        const float* row = xirow + (size_t)d * 1024;
        float4 wc = *(const float4*)&wconv[d * 4];     // uniform scalar loads
        float v = row[p];                              // coalesced
        float hv = 0.f;
        if (lane < 3 && p0 > 0) hv = row[p0 - 3 + lane];
        float h0 = __shfl(hv, 0), h1 = __shfl(hv, 1), h2 = __shfl(hv, 2);
        float vm1 = __shfl_up(v, 1); if (lane < 1) vm1 = h2;
        float vm2 = __shfl_up(v, 2); if (lane < 2) vm2 = (lane == 1) ? h2 : h1;
        float vm3 = __shfl_up(v, 3); if (lane < 3) vm3 = (lane == 2) ? h2 : (lane == 1) ? h1 : h0;
        float o = bconv[d];
        o += vm3 * wc.x;
        o += vm2 * wc.y;
        o += vm1 * wc.z;
        o += v   * wc.w;
        o = o * sigmoidf_(o);                          // silu
        xcrow[(size_t)d * 1024 + p] = o;               // coalesced global store
        sX[d * 64 + lane] = o;                         // conflict-free (2 lanes/bank)
    }
    __syncthreads();                                   // sX full; sWr replicas ready

    // ---- phase 3: x-proj, K = 128; weights via LDS broadcast ----
    float acc[5];
#pragma unroll
    for (int jj = 0; jj < 5; ++jj) acc[jj] = 0.f;
#pragma unroll 4
    for (int d = 0; d < 128; ++d) {
        float xcv = sX[d * 64 + lane];
        const float* wr = &sWr[(wq * 128 + d) * 6];    // wave-uniform -> broadcast
        float2 wA = *(const float2*)(wr);
        float2 wB = *(const float2*)(wr + 2);
        acc[0] += wA.x * xcv; acc[1] += wA.y * xcv;
        acc[2] += wB.x * xcv; acc[3] += wB.y * xcv;
        if (wq < 4) acc[4] += wr[4] * xcv;             // wave-uniform branch
    }

    float* Bm = ws + O_BM + (size_t)seq * 16384;
    float* Cm = ws + O_CM + (size_t)seq * 16384;
#pragma unroll
    for (int jj = 0; jj < 5; ++jj) {
        if (jj < jcount) {
            int j = j0 + jj;
            if (j < 4) continue;                       // dtp consumed in phase 4 (wq0 j0-3)
            float t = acc[jj];
            if (j < 20) Bm[(size_t)(j - 4)  * 1024 + p] = t;
            else        Cm[(size_t)(j - 20) * 1024 + p] = t;
        }
    }
    if (wq == 0)
        *(float4*)&sDtp4[lane * 4] = make_float4(acc[0], acc[1], acc[2], acc[3]);
    __syncthreads();                                   // sWr reads done; sDtp4 ready

    // ---- sB5 overlay (dead sWr region): B rows [p_local][s], from registers ----
#pragma unroll
    for (int jj = 0; jj < 5; ++jj) {
        if (jj < jcount) {
            int j = j0 + jj;                           // wave-uniform per jj
            if (j >= 4 && j < 20) sB5[lane * 20 + (j - 4)] = acc[jj];
        }
    }

    // ---- phase 4: dt + dx -> global (16 rows/wave) ----
    float* dtg = ws + O_DT + (size_t)seq * 131072;
    float* dxg = ws + O_DX + (size_t)seq * 131072;
    float4 qv = *(const float4*)&sDtp4[lane * 4];
#pragma unroll 4
    for (int dd = 0; dd < 16; ++dd) {
        int d = wq * 16 + dd;                          // uniform
        float4 wv = *(const float4*)&wdt[d * 4];       // uniform scalar loads
        float t = bdt[d] + qv.x*wv.x + qv.y*wv.y + qv.z*wv.z + qv.w*wv.w;
        float dt = softplusf_(t);
        float dx = dt * sX[d * 64 + lane];
        dtg[(size_t)d * 1024 + p] = dt;
        dxg[(size_t)d * 1024 + p] = dx;
    }
    __syncthreads();                                   // dt/dx stores drained; sB5 ready

    // ---- phase 5 (fused k3a): chunk-local scan, ONE d-row per thread, 4 states ----
    {
        int dA = tid >> 2;                             // 0..127
        int s05 = (tid & 3) * 4;
        float a2[4];
        {
            float4 a0 = *(const float4*)(alog + dA * 16 + s05);
            a2[0] = -fexp2(a0.x * L2E) * L2E; a2[1] = -fexp2(a0.y * L2E) * L2E;
            a2[2] = -fexp2(a0.z * L2E) * L2E; a2[3] = -fexp2(a0.w * L2E) * L2E;
        }
        const float* dtA = ws + O_DT + (size_t)seq * 131072 + (size_t)dA * 1024 + p0;
        const float* dxA = ws + O_DX + (size_t)seq * 131072 + (size_t)dA * 1024 + p0;
        float* hp0 = ws + O_HP + (size_t)(seq * 32 + ptile * 2) * 4096;
#pragma unroll
        for (int cc = 0; cc < 2; ++cc) {
            float h[4];
#pragma unroll
            for (int i = 0; i < 4; ++i) h[i] = 0.f;
            float sdtA = 0.f;
            for (int q4 = 0; q4 < 8; ++q4) {
                float4 t0 = *(const float4*)&dtA[cc * 32 + q4 * 4];
                float4 x0 = *(const float4*)&dxA[cc * 32 + q4 * 4];
                float t0a[4] = {t0.x, t0.y, t0.z, t0.w};
                float x0a[4] = {x0.x, x0.y, x0.z, x0.w};
#pragma unroll
                for (int k = 0; k < 4; ++k) {
                    int li = q4 * 4 + k;
                    float4 Bv = *(const float4*)&sB5[(cc * 32 + li) * 20 + s05];
                    float bv[4] = {Bv.x, Bv.y, Bv.z, Bv.w};
                    float dt0 = t0a[k];
                    float dx0 = x0a[k];
                    sdtA += dt0;
#pragma unroll
                    for (int ss = 0; ss < 4; ++ss) {
                        float e0 = fexp2(dt0 * a2[ss]);
                        h[ss] = e0 * h[ss] + dx0 * bv[ss];
                    }
                }
            }
            float* hp = hp0 + (size_t)cc * 4096;
            *(float4*)&hp[dA * 16 + s05] = make_float4(
                fexp2(a2[0] * sdtA), fexp2(a2[1] * sdtA),
                fexp2(a2[2] * sdtA), fexp2(a2[3] * sdtA));
            *(float4*)&hp[2048 + dA * 16 + s05] = make_float4(h[0], h[1], h[2], h[3]);
        }
    }
}

// ---------------- a2 preload for k3cd (d0, d0+1 pairing) ----------------
__device__ __forceinline__ void a2_preload(const float* alog, int d0, int s0, float* a2)
{
    float4 a0 = *(const float4*)(alog + d0 * 16 + s0);
    float4 a1 = *(const float4*)(alog + (d0 + 1) * 16 + s0);
    a2[0] = -fexp2(a0.x * L2E) * L2E; a2[1] = -fexp2(a0.y * L2E) * L2E;
    a2[2] = -fexp2(a0.z * L2E) * L2E; a2[3] = -fexp2(a0.w * L2E) * L2E;
    a2[4] = -fexp2(a1.x * L2E) * L2E; a2[5] = -fexp2(a1.y * L2E) * L2E;
    a2[6] = -fexp2(a1.z * L2E) * L2E; a2[7] = -fexp2(a1.w * L2E) * L2E;
}

// phase B: sequential prefix compose. grid 256 = 32 seq * 8 dgroups, 1 state/thread.
__global__ __launch_bounds__(256) void k3b_compose(float* __restrict__ ws)
{
    int seq = blockIdx.x >> 3, dg = blockIdx.x & 7;
    int idx = dg * 256 + threadIdx.x;
    float h = 0.f;
    float* hpb = ws + O_HP + (size_t)seq * 32 * 4096;
    float P = hpb[idx];
    float E = hpb[2048 + idx];
    for (int c = 0; c < 32; ++c) {
        float* hp = hpb + (size_t)c * 4096;
        float Pn = 0.f, En = 0.f;
        if (c < 31) { Pn = hp[4096 + idx]; En = hp[4096 + 2048 + idx]; }
        hp[idx] = h;
        h = P * h + E;
        P = Pn; E = En;
    }
}

// ================= K3CD: rescan + gate + out-proj + skip =================
// grid 1024 = 32 seq * 32 ch; block 256. LDS 22.5 KB.
__global__ __launch_bounds__(256) void k3cd(
    const float* __restrict__ alog,
    const float* __restrict__ x0, const float* __restrict__ x1,
    const float* __restrict__ x2, const float* __restrict__ x3,
    const float* __restrict__ g1, const float* __restrict__ be1,
    const float* __restrict__ g2, const float* __restrict__ be2,
    const float* __restrict__ g3, const float* __restrict__ be3,
    const float* __restrict__ g4, const float* __restrict__ be4,
    const float* __restrict__ dpar, const float* __restrict__ woutp,
    const float* __restrict__ skipp, float* __restrict__ ws,
    float* __restrict__ out)
{
    __shared__ __align__(16) float sY[128 * 36];     // y, then gated g
    __shared__ __align__(16) float sB[32 * 16];
    __shared__ __align__(16) float sC[32 * 16];
    int bid = blockIdx.x;
    int seq = bid >> 5, ch = bid & 31;
    int branch = seq >> 3, b = seq & 7;
    int lb = ch * 32;
    int tid = threadIdx.x;
    int sq = tid & 3;
    int d0 = (tid >> 2) * 2, s0 = sq * 4;

    float a2[8];
    a2_preload(alog, d0, s0, a2);

    const float* Bmg = ws + O_BM + (size_t)seq * 16384;
    const float* Cmg = ws + O_CM + (size_t)seq * 16384;
    for (int i = tid; i < 512; i += 256) {
        int s = i >> 5, li = i & 31;
        sB[li * 16 + s] = Bmg[(size_t)s * 1024 + lb + li];
        sC[li * 16 + s] = Cmg[(size_t)s * 1024 + lb + li];
    }

    const float* hp = ws + O_HP + (size_t)(seq * 32 + ch) * 4096;
    float4 H0 = *(const float4*)&hp[d0 * 16 + s0];
    float4 H1 = *(const float4*)&hp[(d0 + 1) * 16 + s0];
    float h[8] = {H0.x, H0.y, H0.z, H0.w, H1.x, H1.y, H1.z, H1.w};
    __syncthreads();

    const float* r0t = ws + O_DT + (size_t)seq * 131072 + (size_t)d0 * 1024 + lb;
    const float* r1t = r0t + 1024;
    const float* r0x = ws + O_DX + (size_t)seq * 131072 + (size_t)d0 * 1024 + lb;
    const float* r1x = r0x + 1024;

    // ---- rescan: y into sY (stride 36) ----
    for (int q4 = 0; q4 < 8; ++q4) {
        float4 t0 = *(const float4*)&r0t[q4 * 4];
        float4 t1 = *(const float4*)&r1t[q4 * 4];
        float4 x0v = *(const float4*)&r0x[q4 * 4];
        float4 x1v = *(const float4*)&r1x[q4 * 4];
        float t0a[4] = {t0.x, t0.y, t0.z, t0.w};
        float t1a[4] = {t1.x, t1.y, t1.z, t1.w};
        float x0a[4] = {x0v.x, x0v.y, x0v.z, x0v.w};
        float x1a[4] = {x1v.x, x1v.y, x1v.z, x1v.w};
#pragma unroll
        for (int k = 0; k < 4; ++k) {
            int li = q4 * 4 + k;
            float dt0 = t0a[k], dt1 = t1a[k];
            float dx0 = x0a[k], dx1 = x1a[k];
            float4 Bv = *(const float4*)&sB[li * 16 + s0];
            float4 Cv = *(const float4*)&sC[li * 16 + s0];
            float bv[4] = {Bv.x, Bv.y, Bv.z, Bv.w};
            float cv[4] = {Cv.x, Cv.y, Cv.z, Cv.w};
            float acc0 = 0.f, acc1 = 0.f;
#pragma unroll
            for (int ss = 0; ss < 4; ++ss) {
                float e0 = fexp2(dt0 * a2[ss]);
                h[ss] = e0 * h[ss] + dx0 * bv[ss];
                acc0 += h[ss] * cv[ss];
                float e1 = fexp2(dt1 * a2[4 + ss]);
                h[4 + ss] = e1 * h[4 + ss] + dx1 * bv[ss];
                acc1 += h[4 + ss] * cv[ss];
            }
            acc0 += __shfl_xor(acc0, 1); acc0 += __shfl_xor(acc0, 2);
            acc1 += __shfl_xor(acc1, 1); acc1 += __shfl_xor(acc1, 2);
            if (sq == 0) {
                sY[d0 * 36 + li]       = acc0;
                sY[(d0 + 1) * 36 + li] = acc1;
            }
        }
    }
    __syncthreads();

    // ---- gate in place: g = (y + D*xc) * silu(z) ----
    const float* zzg = ws + O_Z  + (size_t)seq * 131072;
    const float* xcg = ws + O_XC + (size_t)seq * 131072;
    for (int i = tid; i < 4096; i += 256) {
        int d = i >> 5, li = i & 31;
        float zv  = zzg[(size_t)d * 1024 + lb + li];
        float xcv = xcg[(size_t)d * 1024 + lb + li];
        float yv  = sY[d * 36 + li];
        sY[d * 36 + li] = (yv + dpar[d] * xcv) * (zv * sigmoidf_(zv));
    }
    __syncthreads();

    // ---- out-proj GEMM: out[64c][32p] = Wout[64][128] @ g[128][32] ----
    int ctt = tid >> 3;          // c0 = 2*ctt
    int ptq = tid & 7;           // p0 = 4*ptq
    int c0 = ctt * 2;
    const float* w0p = woutp + (size_t)c0 * 128;
    const float* w1p = w0p + 128;
    float acc[2][4];
#pragma unroll
    for (int i = 0; i < 2; ++i)
#pragma unroll
        for (int j = 0; j < 4; ++j) acc[i][j] = 0.f;
    for (int d4 = 0; d4 < 32; ++d4) {
        float4 wa = *(const float4*)&w0p[d4 * 4];
        float4 wb = *(const float4*)&w1p[d4 * 4];
        float waa[4] = {wa.x, wa.y, wa.z, wa.w};
        float wba[4] = {wb.x, wb.y, wb.z, wb.w};
#pragma unroll
        for (int k = 0; k < 4; ++k) {
            int d = d4 * 4 + k;
            float4 gv = *(const float4*)&sY[d * 36 + ptq * 4];
            acc[0][0] += waa[k] * gv.x; acc[0][1] += waa[k] * gv.y;
            acc[0][2] += waa[k] * gv.z; acc[0][3] += waa[k] * gv.w;
            acc[1][0] += wba[k] * gv.x; acc[1][1] += wba[k] * gv.y;
            acc[1][2] += wba[k] * gv.z; acc[1][3] += wba[k] * gv.w;
        }
    }

    // ---- epilogue: + skip * xn ----
    const float* xin = (branch==0)?x0:(branch==1)?x1:(branch==2)?x2:x3;
    const float* gam = (branch==0)?g1:(branch==1)?g2:(branch==2)?g3:g4;
    const float* bet = (branch==0)?be1:(branch==1)?be2:(branch==2)?be3:be4;
    const float* xb = xin + (size_t)b * 65536;
    int pp = lb + ptq * 4;
    float skipv = skipp[0];
    float4 m4 = *(const float4*)&ws[O_M  + (size_t)seq * 1024 + pp];
    float4 r4 = *(const float4*)&ws[O_RS + (size_t)seq * 1024 + pp];
    float mm[4] = {m4.x, m4.y, m4.z, m4.w};
    float rr[4] = {r4.x, r4.y, r4.z, r4.w};
#pragma unroll
    for (int ci = 0; ci < 2; ++ci) {
        int c = c0 + ci;
        float4 xv = *(const float4*)&xb[(size_t)c * 1024 + pp];
        float xvv[4] = {xv.x, xv.y, xv.z, xv.w};
        float gc = gam[c], bc = bet[c];
        float o[4];
#pragma unroll
        for (int pi = 0; pi < 4; ++pi) {
            float xn = (xvv[pi] - mm[pi]) * rr[pi] * gc + bc;
            o[pi] = acc[ci][pi] + skipv * xn;
        }
        *(float4*)&out[((size_t)b * 256 + branch * 64 + c) * 1024 + pp] =
            make_float4(o[0], o[1], o[2], o[3]);
    }
}

// ---------------- launch ----------------
extern "C" void kernel_launch(void* const* d_in, const int* in_sizes, int n_in,
                              void* d_out, int out_size, void* d_ws, size_t ws_size,
                              hipStream_t stream) {
    float* ws = (float*)d_ws;
    auto f = [&](int i) { return (const float*)d_in[i]; };
    hipLaunchKernelGGL(k1_ln_inproj, dim3(512), dim3(256), 0, stream,
        f(0), f(1), f(2), f(3), f(13),
        f(4), f(5), f(6), f(7), f(8), f(9), f(10), f(11), ws);
    hipLaunchKernelGGL(k2_conv_proj, dim3(512), dim3(512), 0, stream,
        f(14), f(15), f(16), f(17), f(18), f(19), ws);
    hipLaunchKernelGGL(k3b_compose, dim3(256), dim3(256), 0, stream, ws);
    hipLaunchKernelGGL(k3cd, dim3(1024), dim3(256), 0, stream,
        f(19),
        f(0), f(1), f(2), f(3),
        f(4), f(5), f(6), f(7), f(8), f(9), f(10), f(11),
        f(20), f(21), f(12), ws, (float*)d_out);
}